// Round 8
// baseline (2133.062 us; speedup 1.0000x reference)
//
#include <hip/hip_runtime.h>
#include <hip/hip_bf16.h>

#define HID 128
#define SEQ 2048
#define BATCH 64
#define NOUT 512

typedef __attribute__((ext_vector_type(8))) short bf16x8;
typedef __attribute__((ext_vector_type(4))) float f32x4;

__device__ __forceinline__ short f2bf(float f) {
    unsigned u = __float_as_uint(f);
    unsigned r = u + 0x7fffu + ((u >> 16) & 1u);   // RNE
    return (short)(r >> 16);
}

__device__ __forceinline__ float fast_sigmoid(float x) {
    return 1.0f / (1.0f + __expf(-x));
}

__device__ __forceinline__ float fast_tanh(float x) {
    return 1.0f - 2.0f / (__expf(2.0f * x) + 1.0f);
}

// lane ^ 8 within each 16-lane row: DPP ROW_ROR:8. Pure VALU (~2cyc);
// replaced DS-pipe shuffles in round 5/6 (verified: conflicts -> 0).
__device__ __forceinline__ float dpp_ror8(float x) {
    int y = __builtin_amdgcn_update_dpp(0, __builtin_bit_cast(int, x),
                                        0x128, 0xF, 0xF, true);
    return __builtin_bit_cast(float, y);
}

// One MFMA A-fragment from an f32 [rows][128] matrix:
// lane holds rows[row][kcol..kcol+7] as bf16x8.
__device__ __forceinline__ bf16x8 load_wfrag(const float* __restrict__ W,
                                             int row, int kcol) {
    const float* wp = W + (size_t)row * HID + kcol;
    float4 x = *(const float4*)wp;
    float4 y = *(const float4*)(wp + 4);
    bf16x8 f;
    f[0] = f2bf(x.x); f[1] = f2bf(x.y); f[2] = f2bf(x.z); f[3] = f2bf(x.w);
    f[4] = f2bf(y.x); f[5] = f2bf(y.y); f[6] = f2bf(y.z); f[7] = f2bf(y.w);
    return f;
}

// ---------------------------------------------------------------------------
// FUSED GRU recurrence + output projection. 8 blocks x 8 batches; 512 thr.
//
// ERRATA from rounds 0-7: FETCH_SIZE is KB, not MB. 831.5 KB = inputs +
// write-allocate; there was NEVER scratch spill traffic. The kernel is a
// pure latency-chain at ~1600cyc/step with the CU ~75% idle (MfmaUtil 23%,
// active-VALU ~68%, rest stalls).
//
// This round exploits that idleness: the H fragments (hf0..3) read from LDS
// for the recurrence are EXACTLY the B-operand fragments the projection
// out[t-1] = fc_W . h_t needs (batch = same 16-lane axis). Wave j holds
// fc_W rows [64j,64j+64) as 16 registered fragments (same layout as the
// harness-verified wprep/proj pair) and issues 16 extra MFMAs per step into
// the idle matrix pipe + 4 fire-and-forget nt stores. Deletes: proj kernel
// (~280us tail all session), wprep, the hs workspace and its 33MBx2 HBM
// round-trip, and the per-step hs store.
//
// Recurrence body is byte-identical to the round-7 passing kernel
// (swizzled LDS, DPP rebalance, masked H reads, bias-seeded accumulators,
// one raw lgkm-only barrier per step).
// ---------------------------------------------------------------------------
__global__ __launch_bounds__(512, 1) void gru_fused(
    const float* __restrict__ latent,   // [BATCH][HID]
    const float* __restrict__ W_hh,     // [3*HID][HID]
    const float* __restrict__ b_ih,     // [3*HID]
    const float* __restrict__ b_hh,     // [3*HID]
    const float* __restrict__ fc_W,     // [NOUT][HID]
    const float* __restrict__ fc_b,     // [NOUT]
    float* __restrict__ out)            // [BATCH][SEQ][NOUT]
{
    const int tid  = threadIdx.x;          // 0..511
    const int j    = tid >> 6;             // wave 0..7
    const int lane = tid & 63;
    const int rr   = lane & 15;            // 16-axis: batch col of D
    const int g    = lane >> 4;            // 0..3
    const int hi   = (lane >> 3) & 1;
    const int br   = rr & 7;               // batch row 0..7
    const int h0   = 16 * j + 4 * g + 2 * hi;  // lane's 2 h columns
    const int n0l  = 16 * j + 4 * g;           // lane's 4 gate rows

    // [2 buffers][16 rows][128 cols] bf16, 16B-block swizzled within rows
    __shared__ __align__(16) __hip_bfloat16 Hl[2][2048];

    // ---- W_hh fragments: 12 named registers (r/z/n gates, k-slices) ----
    const int wrow = j * 16 + rr;
    bf16x8 wr0 = load_wfrag(W_hh, wrow,       0 * 32 + g * 8);
    bf16x8 wr1 = load_wfrag(W_hh, wrow,       1 * 32 + g * 8);
    bf16x8 wr2 = load_wfrag(W_hh, wrow,       2 * 32 + g * 8);
    bf16x8 wr3 = load_wfrag(W_hh, wrow,       3 * 32 + g * 8);
    bf16x8 wz0 = load_wfrag(W_hh, wrow + 128, 0 * 32 + g * 8);
    bf16x8 wz1 = load_wfrag(W_hh, wrow + 128, 1 * 32 + g * 8);
    bf16x8 wz2 = load_wfrag(W_hh, wrow + 128, 2 * 32 + g * 8);
    bf16x8 wz3 = load_wfrag(W_hh, wrow + 128, 3 * 32 + g * 8);
    bf16x8 wn0 = load_wfrag(W_hh, wrow + 256, 0 * 32 + g * 8);
    bf16x8 wn1 = load_wfrag(W_hh, wrow + 256, 1 * 32 + g * 8);
    bf16x8 wn2 = load_wfrag(W_hh, wrow + 256, 2 * 32 + g * 8);
    bf16x8 wn3 = load_wfrag(W_hh, wrow + 256, 3 * 32 + g * 8);

    // ---- fc_W fragments: wave j owns out-cols [64j, 64j+64) = 4 tiles ----
    const int prow = j * 64 + rr;          // + tt*16 per tile
    bf16x8 fw00 = load_wfrag(fc_W, prow +  0, 0 * 32 + g * 8);
    bf16x8 fw01 = load_wfrag(fc_W, prow +  0, 1 * 32 + g * 8);
    bf16x8 fw02 = load_wfrag(fc_W, prow +  0, 2 * 32 + g * 8);
    bf16x8 fw03 = load_wfrag(fc_W, prow +  0, 3 * 32 + g * 8);
    bf16x8 fw10 = load_wfrag(fc_W, prow + 16, 0 * 32 + g * 8);
    bf16x8 fw11 = load_wfrag(fc_W, prow + 16, 1 * 32 + g * 8);
    bf16x8 fw12 = load_wfrag(fc_W, prow + 16, 2 * 32 + g * 8);
    bf16x8 fw13 = load_wfrag(fc_W, prow + 16, 3 * 32 + g * 8);
    bf16x8 fw20 = load_wfrag(fc_W, prow + 32, 0 * 32 + g * 8);
    bf16x8 fw21 = load_wfrag(fc_W, prow + 32, 1 * 32 + g * 8);
    bf16x8 fw22 = load_wfrag(fc_W, prow + 32, 2 * 32 + g * 8);
    bf16x8 fw23 = load_wfrag(fc_W, prow + 32, 3 * 32 + g * 8);
    bf16x8 fw30 = load_wfrag(fc_W, prow + 48, 0 * 32 + g * 8);
    bf16x8 fw31 = load_wfrag(fc_W, prow + 48, 1 * 32 + g * 8);
    bf16x8 fw32 = load_wfrag(fc_W, prow + 48, 2 * 32 + g * 8);
    bf16x8 fw33 = load_wfrag(fc_W, prow + 48, 3 * 32 + g * 8);

    // ---- recurrence accumulator bias seeds ----
    f32x4 seedR, seedZ, seedN;
    {
        float4 bi = *(const float4*)&b_ih[n0l];
        float4 bh = *(const float4*)&b_hh[n0l];
        seedR[0] = bi.x + bh.x; seedR[1] = bi.y + bh.y;
        seedR[2] = bi.z + bh.z; seedR[3] = bi.w + bh.w;
        bi = *(const float4*)&b_ih[HID + n0l];
        bh = *(const float4*)&b_hh[HID + n0l];
        seedZ[0] = bi.x + bh.x; seedZ[1] = bi.y + bh.y;
        seedZ[2] = bi.z + bh.z; seedZ[3] = bi.w + bh.w;
        bh = *(const float4*)&b_hh[2 * HID + n0l];
        seedN[0] = bh.x; seedN[1] = bh.y; seedN[2] = bh.z; seedN[3] = bh.w;
    }
    const float2 bin2 = *(const float2*)&b_ih[2 * HID + h0];
    const float bn0 = bin2.x, bn1 = bin2.y;

    // ---- projection bias seeds (lane's 4 out-cols per tile) ----
    const int pcol = j * 64 + g * 4;
    const f32x4 seedP0 = *(const f32x4*)&fc_b[pcol +  0];
    const f32x4 seedP1 = *(const f32x4*)&fc_b[pcol + 16];
    const f32x4 seedP2 = *(const f32x4*)&fc_b[pcol + 32];
    const f32x4 seedP3 = *(const f32x4*)&fc_b[pcol + 48];

    // ---- swizzled LDS element offsets (round-4-proven) ----
    const int re0 = rr * 128 + (((0 * 4 + g) ^ (rr & 7)) << 3);
    const int re1 = rr * 128 + (((1 * 4 + g) ^ (rr & 7)) << 3);
    const int re2 = rr * 128 + (((2 * 4 + g) ^ (rr & 7)) << 3);
    const int re3 = rr * 128 + (((3 * 4 + g) ^ (rr & 7)) << 3);
    const int we = br * 128 + ((((2 * j) + (g >> 1)) ^ br) << 3)
                 + 4 * (g & 1) + 2 * hi;

    // ---- init: hold regs + H buffer 0 ----
    const int batch = blockIdx.x * 8 + br;
    float2 h02 = *(const float2*)&latent[batch * HID + h0];
    float hold0 = h02.x, hold1 = h02.y;
    {
        unsigned v = (unsigned short)f2bf(hold0)
                   | ((unsigned)(unsigned short)f2bf(hold1) << 16);
        *(unsigned*)&Hl[0][we] = v;
    }
    __syncthreads();

    // out pointer for this lane (row 0; stores start at t=1 -> row t-1)
    float* op = out + ((size_t)batch * SEQ) * NOUT + pcol;

    bf16x8 hf0 = {}, hf1 = {}, hf2 = {}, hf3 = {};
    if (rr < 8) {                       // hf = h_0 (latent)
        const __hip_bfloat16* hb = &Hl[0][0];
        hf0 = *(const bf16x8*)&hb[re0];
        hf1 = *(const bf16x8*)&hb[re1];
        hf2 = *(const bf16x8*)&hb[re2];
        hf3 = *(const bf16x8*)&hb[re3];
    }

    int p = 0;
    for (int t = 0; t <= SEQ; t++) {
        // ---------------- recurrence MFMAs (h_t -> gates) ----------------
        f32x4 a0, a1, a2;
        if (t < SEQ) {
            a0 = seedR;  a1 = seedZ;  a2 = seedN;
            a0 = __builtin_amdgcn_mfma_f32_16x16x32_bf16(wr0, hf0, a0, 0, 0, 0);
            a1 = __builtin_amdgcn_mfma_f32_16x16x32_bf16(wz0, hf0, a1, 0, 0, 0);
            a2 = __builtin_amdgcn_mfma_f32_16x16x32_bf16(wn0, hf0, a2, 0, 0, 0);
            a0 = __builtin_amdgcn_mfma_f32_16x16x32_bf16(wr1, hf1, a0, 0, 0, 0);
            a1 = __builtin_amdgcn_mfma_f32_16x16x32_bf16(wz1, hf1, a1, 0, 0, 0);
            a2 = __builtin_amdgcn_mfma_f32_16x16x32_bf16(wn1, hf1, a2, 0, 0, 0);
            a0 = __builtin_amdgcn_mfma_f32_16x16x32_bf16(wr2, hf2, a0, 0, 0, 0);
            a1 = __builtin_amdgcn_mfma_f32_16x16x32_bf16(wz2, hf2, a1, 0, 0, 0);
            a2 = __builtin_amdgcn_mfma_f32_16x16x32_bf16(wn2, hf2, a2, 0, 0, 0);
            a0 = __builtin_amdgcn_mfma_f32_16x16x32_bf16(wr3, hf3, a0, 0, 0, 0);
            a1 = __builtin_amdgcn_mfma_f32_16x16x32_bf16(wz3, hf3, a1, 0, 0, 0);
            a2 = __builtin_amdgcn_mfma_f32_16x16x32_bf16(wn3, hf3, a2, 0, 0, 0);
        }

        // ------- projection of the SAME h_t -> out row t-1 (t >= 1) ------
        // Issued into the matrix pipe's idle window; results feed only
        // fire-and-forget nt stores (never the recurrence critical path).
        if (t > 0) {
            f32x4 pa0 = seedP0, pa1 = seedP1, pa2 = seedP2, pa3 = seedP3;
            pa0 = __builtin_amdgcn_mfma_f32_16x16x32_bf16(fw00, hf0, pa0, 0, 0, 0);
            pa1 = __builtin_amdgcn_mfma_f32_16x16x32_bf16(fw10, hf0, pa1, 0, 0, 0);
            pa2 = __builtin_amdgcn_mfma_f32_16x16x32_bf16(fw20, hf0, pa2, 0, 0, 0);
            pa3 = __builtin_amdgcn_mfma_f32_16x16x32_bf16(fw30, hf0, pa3, 0, 0, 0);
            pa0 = __builtin_amdgcn_mfma_f32_16x16x32_bf16(fw01, hf1, pa0, 0, 0, 0);
            pa1 = __builtin_amdgcn_mfma_f32_16x16x32_bf16(fw11, hf1, pa1, 0, 0, 0);
            pa2 = __builtin_amdgcn_mfma_f32_16x16x32_bf16(fw21, hf1, pa2, 0, 0, 0);
            pa3 = __builtin_amdgcn_mfma_f32_16x16x32_bf16(fw31, hf1, pa3, 0, 0, 0);
            pa0 = __builtin_amdgcn_mfma_f32_16x16x32_bf16(fw02, hf2, pa0, 0, 0, 0);
            pa1 = __builtin_amdgcn_mfma_f32_16x16x32_bf16(fw12, hf2, pa1, 0, 0, 0);
            pa2 = __builtin_amdgcn_mfma_f32_16x16x32_bf16(fw22, hf2, pa2, 0, 0, 0);
            pa3 = __builtin_amdgcn_mfma_f32_16x16x32_bf16(fw32, hf2, pa3, 0, 0, 0);
            pa0 = __builtin_amdgcn_mfma_f32_16x16x32_bf16(fw03, hf3, pa0, 0, 0, 0);
            pa1 = __builtin_amdgcn_mfma_f32_16x16x32_bf16(fw13, hf3, pa1, 0, 0, 0);
            pa2 = __builtin_amdgcn_mfma_f32_16x16x32_bf16(fw23, hf3, pa2, 0, 0, 0);
            pa3 = __builtin_amdgcn_mfma_f32_16x16x32_bf16(fw33, hf3, pa3, 0, 0, 0);
            if (rr < 8) {               // D cols 8-15 are garbage batches
                __builtin_nontemporal_store(pa0, (f32x4*)(op +  0));
                __builtin_nontemporal_store(pa1, (f32x4*)(op + 16));
                __builtin_nontemporal_store(pa2, (f32x4*)(op + 32));
                __builtin_nontemporal_store(pa3, (f32x4*)(op + 48));
            }
            op += NOUT;
        }

        if (t < SEQ) {
            // rebalance: hi half adopts regs 2,3 from lane^8 (VALU DPP)
            float s00 = dpp_ror8(a0[2]), s01 = dpp_ror8(a0[3]);
            float s10 = dpp_ror8(a1[2]), s11 = dpp_ror8(a1[3]);
            float s20 = dpp_ror8(a2[2]), s21 = dpp_ror8(a2[3]);
            float gr0 = hi ? s00 : a0[0], gr1 = hi ? s01 : a0[1];
            float gz0 = hi ? s10 : a1[0], gz1 = hi ? s11 : a1[1];
            float gn0 = hi ? s20 : a2[0], gn1 = hi ? s21 : a2[1];

            float r0 = fast_sigmoid(gr0);
            float z0 = fast_sigmoid(gz0);
            float n0 = fast_tanh(bn0 + r0 * gn0);
            float hn0 = (1.0f - z0) * n0 + z0 * hold0;
            hold0 = hn0;
            float r1 = fast_sigmoid(gr1);
            float z1 = fast_sigmoid(gz1);
            float n1 = fast_tanh(bn1 + r1 * gn1);
            float hn1 = (1.0f - z1) * n1 + z1 * hold1;
            hold1 = hn1;

            unsigned v = (unsigned short)f2bf(hn0)
                       | ((unsigned)(unsigned short)f2bf(hn1) << 16);
            *(unsigned*)&Hl[p ^ 1][we] = v;    // next step's H

            // LDS-only drain + raw barrier (no vmcnt: stores stay in flight)
            asm volatile("s_waitcnt lgkmcnt(0)" ::: "memory");
            __builtin_amdgcn_s_barrier();
            asm volatile("" ::: "memory");
            p ^= 1;

            if (rr < 8) {                      // hf = h_{t+1}
                const __hip_bfloat16* hb = &Hl[p][0];
                hf0 = *(const bf16x8*)&hb[re0];
                hf1 = *(const bf16x8*)&hb[re1];
                hf2 = *(const bf16x8*)&hb[re2];
                hf3 = *(const bf16x8*)&hb[re3];
            }
        }
    }
}

extern "C" void kernel_launch(void* const* d_in, const int* in_sizes, int n_in,
                              void* d_out, int out_size, void* d_ws, size_t ws_size,
                              hipStream_t stream) {
    const float* latent = (const float*)d_in[0];   // (64,128)
    const float* W_hh   = (const float*)d_in[1];   // (384,128)
    const float* b_ih   = (const float*)d_in[2];   // (384,)
    const float* b_hh   = (const float*)d_in[3];   // (384,)
    const float* fc_W   = (const float*)d_in[4];   // (512,128)
    const float* fc_b   = (const float*)d_in[5];   // (512,)
    float* out = (float*)d_out;                    // (64,2048,512)

    gru_fused<<<8, 512, 0, stream>>>(latent, W_hh, b_ih, b_hh, fc_W, fc_b, out);
}

// Round 9
// 1241.792 us; speedup vs baseline: 1.7177x; 1.7177x over previous
//
#include <hip/hip_runtime.h>
#include <hip/hip_bf16.h>

#define HID 128
#define SEQ 2048
#define BATCH 64
#define NOUT 512

typedef __attribute__((ext_vector_type(8))) short bf16x8;
typedef __attribute__((ext_vector_type(4))) float f32x4;

__device__ __forceinline__ short f2bf(float f) {
    unsigned u = __float_as_uint(f);
    unsigned r = u + 0x7fffu + ((u >> 16) & 1u);   // RNE
    return (short)(r >> 16);
}

// Hardware reciprocal (~1ulp in 2^-22): without fast-math, hipcc lowers
// float division to the IEEE v_div_scale/v_div_fmas/v_div_fixup sequence
// (~10 VALU instr, ~30cyc latency). Round-7 counters showed active-CU
// VALUBusy ~68% (1100cyc/step) vs ~350 modeled -- 4 divisions per
// thread-step, 2 serial on the r->n chain, are the prime suspect.
__device__ __forceinline__ float fast_rcp(float x) {
    float y;
    asm("v_rcp_f32 %0, %1" : "=v"(y) : "v"(x));
    return y;
}

__device__ __forceinline__ float fast_sigmoid(float x) {
    return fast_rcp(1.0f + __expf(-x));
}

__device__ __forceinline__ float fast_tanh(float x) {
    return 1.0f - 2.0f * fast_rcp(__expf(2.0f * x) + 1.0f);
}

// lane ^ 8 within each 16-lane row: DPP ROW_ROR:8. Pure VALU (~2cyc);
// replaced DS-pipe shuffles in round 5/6 (verified: conflicts -> 0).
__device__ __forceinline__ float dpp_ror8(float x) {
    int y = __builtin_amdgcn_update_dpp(0, __builtin_bit_cast(int, x),
                                        0x128, 0xF, 0xF, true);
    return __builtin_bit_cast(float, y);
}

// One MFMA A-fragment from an f32 [rows][128] matrix:
// lane holds rows[row][kcol..kcol+7] as bf16x8.
__device__ __forceinline__ bf16x8 load_wfrag(const float* __restrict__ W,
                                             int row, int kcol) {
    const float* wp = W + (size_t)row * HID + kcol;
    float4 x = *(const float4*)wp;
    float4 y = *(const float4*)(wp + 4);
    bf16x8 f;
    f[0] = f2bf(x.x); f[1] = f2bf(x.y); f[2] = f2bf(x.z); f[3] = f2bf(x.w);
    f[4] = f2bf(y.x); f[5] = f2bf(y.y); f[6] = f2bf(y.z); f[7] = f2bf(y.w);
    return f;
}

// ---------------------------------------------------------------------------
// MFMA GRU recurrence. 8 blocks x 8 batches; 512 threads = 8 waves.
// Round-7 verified structure (1380us). Round-9 changes:
//   1. rcp instead of IEEE division in sigmoid/tanh (see fast_rcp note)
//   2. s_setprio(1) around the MFMA cluster (waves are skewed by the LDS
//      read queue -> scheduler has role diversity to arbitrate)
// ERRATA (round 8): fusing the projection here is a loss -- per-CU matrix
// time is #MFMA x 4.85cyc regardless of "idle windows"; +16 MFMA/wave cost
// exactly +620cyc/step. Proj stays a separate ~84us kernel.
// ---------------------------------------------------------------------------
__global__ __launch_bounds__(512, 1) void gru_seq(
    const float* __restrict__ latent,   // [BATCH][HID]
    const float* __restrict__ W_hh,     // [3*HID][HID]
    const float* __restrict__ b_ih,     // [3*HID]
    const float* __restrict__ b_hh,     // [3*HID]
    __hip_bfloat16* __restrict__ hs)    // [BATCH][SEQ][HID]  (bf16)
{
    const int tid  = threadIdx.x;          // 0..511
    const int j    = tid >> 6;             // wave 0..7 -> n-tiles {j,j+8,j+16}
    const int lane = tid & 63;
    const int rr   = lane & 15;            // operand 16-axis / D batch col
    const int g    = lane >> 4;            // 0..3
    const int hi   = (lane >> 3) & 1;      // upper half of 16-group
    const int br   = rr & 7;               // batch row 0..7
    const int h0   = 16 * j + 4 * g + 2 * hi;  // this lane's 2 h columns
    const int n0l  = 16 * j + 4 * g;           // this lane's 4 gate rows

    // [2 buffers][16 rows][128 cols] bf16, 16B-block swizzled within rows
    __shared__ __align__(16) __hip_bfloat16 Hl[2][2048];

    // ---- W fragments: 12 named registers ----
    const int wrow = j * 16 + rr;
    bf16x8 wr0 = load_wfrag(W_hh, wrow,       0 * 32 + g * 8);
    bf16x8 wr1 = load_wfrag(W_hh, wrow,       1 * 32 + g * 8);
    bf16x8 wr2 = load_wfrag(W_hh, wrow,       2 * 32 + g * 8);
    bf16x8 wr3 = load_wfrag(W_hh, wrow,       3 * 32 + g * 8);
    bf16x8 wz0 = load_wfrag(W_hh, wrow + 128, 0 * 32 + g * 8);
    bf16x8 wz1 = load_wfrag(W_hh, wrow + 128, 1 * 32 + g * 8);
    bf16x8 wz2 = load_wfrag(W_hh, wrow + 128, 2 * 32 + g * 8);
    bf16x8 wz3 = load_wfrag(W_hh, wrow + 128, 3 * 32 + g * 8);
    bf16x8 wn0 = load_wfrag(W_hh, wrow + 256, 0 * 32 + g * 8);
    bf16x8 wn1 = load_wfrag(W_hh, wrow + 256, 1 * 32 + g * 8);
    bf16x8 wn2 = load_wfrag(W_hh, wrow + 256, 2 * 32 + g * 8);
    bf16x8 wn3 = load_wfrag(W_hh, wrow + 256, 3 * 32 + g * 8);

    // ---- accumulator bias seeds (lane's 4 gate rows n0l..n0l+3) ----
    f32x4 seedR, seedZ, seedN;
    {
        float4 bi = *(const float4*)&b_ih[n0l];
        float4 bh = *(const float4*)&b_hh[n0l];
        seedR[0] = bi.x + bh.x; seedR[1] = bi.y + bh.y;
        seedR[2] = bi.z + bh.z; seedR[3] = bi.w + bh.w;
        bi = *(const float4*)&b_ih[HID + n0l];
        bh = *(const float4*)&b_hh[HID + n0l];
        seedZ[0] = bi.x + bh.x; seedZ[1] = bi.y + bh.y;
        seedZ[2] = bi.z + bh.z; seedZ[3] = bi.w + bh.w;
        bh = *(const float4*)&b_hh[2 * HID + n0l];
        seedN[0] = bh.x; seedN[1] = bh.y; seedN[2] = bh.z; seedN[3] = bh.w;
    }
    const float2 bin2 = *(const float2*)&b_ih[2 * HID + h0];
    const float bn0 = bin2.x, bn1 = bin2.y;

    // ---- swizzled LDS element offsets (round-4-proven) ----
    const int re0 = rr * 128 + (((0 * 4 + g) ^ (rr & 7)) << 3);
    const int re1 = rr * 128 + (((1 * 4 + g) ^ (rr & 7)) << 3);
    const int re2 = rr * 128 + (((2 * 4 + g) ^ (rr & 7)) << 3);
    const int re3 = rr * 128 + (((3 * 4 + g) ^ (rr & 7)) << 3);
    const int we = br * 128 + ((((2 * j) + (g >> 1)) ^ br) << 3)
                 + 4 * (g & 1) + 2 * hi;

    // ---- init: hold regs + H buffer 0 ----
    const int batch = blockIdx.x * 8 + br;
    float2 h02 = *(const float2*)&latent[batch * HID + h0];
    float hold0 = h02.x, hold1 = h02.y;
    {
        unsigned v = (unsigned short)f2bf(hold0)
                   | ((unsigned)(unsigned short)f2bf(hold1) << 16);
        *(unsigned*)&Hl[0][we] = v;
    }
    __syncthreads();

    __hip_bfloat16* op = hs + ((size_t)batch * SEQ) * HID + h0;

    bf16x8 hf0 = {}, hf1 = {}, hf2 = {}, hf3 = {};
    int p = 0;
    for (int t = 0; t < SEQ; t++) {
        // H fragments: rows 0-7 only (rr>=8 lanes feed discarded D columns)
        const __hip_bfloat16* hb = &Hl[p][0];
        if (rr < 8) {
            hf0 = *(const bf16x8*)&hb[re0];
            hf1 = *(const bf16x8*)&hb[re1];
            hf2 = *(const bf16x8*)&hb[re2];
            hf3 = *(const bf16x8*)&hb[re3];
        }

        f32x4 a0 = seedR;   // r-gate tile j      (bias pre-seeded)
        f32x4 a1 = seedZ;   // z-gate tile j+8
        f32x4 a2 = seedN;   // n-gate tile j+16   (b_hh part)
        __builtin_amdgcn_s_setprio(1);
        a0 = __builtin_amdgcn_mfma_f32_16x16x32_bf16(wr0, hf0, a0, 0, 0, 0);
        a1 = __builtin_amdgcn_mfma_f32_16x16x32_bf16(wz0, hf0, a1, 0, 0, 0);
        a2 = __builtin_amdgcn_mfma_f32_16x16x32_bf16(wn0, hf0, a2, 0, 0, 0);
        a0 = __builtin_amdgcn_mfma_f32_16x16x32_bf16(wr1, hf1, a0, 0, 0, 0);
        a1 = __builtin_amdgcn_mfma_f32_16x16x32_bf16(wz1, hf1, a1, 0, 0, 0);
        a2 = __builtin_amdgcn_mfma_f32_16x16x32_bf16(wn1, hf1, a2, 0, 0, 0);
        a0 = __builtin_amdgcn_mfma_f32_16x16x32_bf16(wr2, hf2, a0, 0, 0, 0);
        a1 = __builtin_amdgcn_mfma_f32_16x16x32_bf16(wz2, hf2, a1, 0, 0, 0);
        a2 = __builtin_amdgcn_mfma_f32_16x16x32_bf16(wn2, hf2, a2, 0, 0, 0);
        a0 = __builtin_amdgcn_mfma_f32_16x16x32_bf16(wr3, hf3, a0, 0, 0, 0);
        a1 = __builtin_amdgcn_mfma_f32_16x16x32_bf16(wz3, hf3, a1, 0, 0, 0);
        a2 = __builtin_amdgcn_mfma_f32_16x16x32_bf16(wn3, hf3, a2, 0, 0, 0);
        __builtin_amdgcn_s_setprio(0);

        // rebalance: hi half adopts regs 2,3 from lane^8 -- pure VALU DPP
        float s00 = dpp_ror8(a0[2]), s01 = dpp_ror8(a0[3]);
        float s10 = dpp_ror8(a1[2]), s11 = dpp_ror8(a1[3]);
        float s20 = dpp_ror8(a2[2]), s21 = dpp_ror8(a2[3]);
        float gr0 = hi ? s00 : a0[0], gr1 = hi ? s01 : a0[1];
        float gz0 = hi ? s10 : a1[0], gz1 = hi ? s11 : a1[1];
        float gn0 = hi ? s20 : a2[0], gn1 = hi ? s21 : a2[1];

        // activations (biases already folded into the accumulators)
        float r0 = fast_sigmoid(gr0);
        float z0 = fast_sigmoid(gz0);
        float n0 = fast_tanh(bn0 + r0 * gn0);
        float hn0 = (1.0f - z0) * n0 + z0 * hold0;
        hold0 = hn0;
        float r1 = fast_sigmoid(gr1);
        float z1 = fast_sigmoid(gz1);
        float n1 = fast_tanh(bn1 + r1 * gn1);
        float hn1 = (1.0f - z1) * n1 + z1 * hold1;
        hold1 = hn1;

        unsigned v = (unsigned short)f2bf(hn0)
                   | ((unsigned)(unsigned short)f2bf(hn1) << 16);
        *(unsigned*)&Hl[p ^ 1][we] = v;    // next step's H (swizzled slot)
        *(unsigned*)op = v;                // history output (not drained)
        op += HID;

        // LDS-only drain + raw barrier: global stores stay in flight
        asm volatile("s_waitcnt lgkmcnt(0)" ::: "memory");
        __builtin_amdgcn_s_barrier();
        asm volatile("" ::: "memory");
        p ^= 1;
    }
}

// ---------------------------------------------------------------------------
// Repack fc_W (f32 [512][128]) into bf16 MFMA fragment order:
//   wfrag[((ct*4 + q)*64 + lane)*8 + j] = bf16(fc_W[ct*16 + (lane&15)]
//                                                  [q*32 + (lane>>4)*8 + j])
// ---------------------------------------------------------------------------
__global__ void wprep(const float* __restrict__ fc_W,
                      __hip_bfloat16* __restrict__ wfrag)
{
    int t = blockIdx.x * 256 + threadIdx.x;      // 0..65535
    int j    = t & 7;
    int lane = (t >> 3) & 63;
    int q    = (t >> 9) & 3;
    int ct   = t >> 11;
    int n = ct * 16 + (lane & 15);
    int k = q * 32 + (lane >> 4) * 8 + j;
    unsigned short v = (unsigned short)f2bf(fc_W[n * HID + k]);
    wfrag[t] = __builtin_bit_cast(__hip_bfloat16, v);
}

// ---------------------------------------------------------------------------
// Projection: out[row][o] = sum_k hs[row][k] * fc_W[o][k] + fc_b[o]
// M = 131072, N = 512, K = 128. bf16 MFMA 16x16x32, operand-swapped.
// Nontemporal stores/loads (round-6, passing). ~84us (near roofline after
// accounting the ~218us fixed harness overhead discovered in round 8).
// ---------------------------------------------------------------------------
__global__ __launch_bounds__(256) void proj_mfma(
    const __hip_bfloat16* __restrict__ hsb,    // [M][128] bf16
    const __hip_bfloat16* __restrict__ wfrag,  // fragment-ordered [32][4][64][8]
    const float* __restrict__ fc_b,            // [512]
    float* __restrict__ out)                   // [M][512] f32
{
    const int lane = threadIdx.x & 63;
    const int wave = threadIdx.x >> 6;
    const int m    = lane & 15;
    const int quad = lane >> 4;

    const long r0 = ((long)blockIdx.x * 4 + wave) * 32;

    bf16x8 bfrag[2][4];                         // hs rows as second operand
    #pragma unroll
    for (int rt = 0; rt < 2; rt++) {
        #pragma unroll
        for (int q = 0; q < 4; q++) {
            const bf16x8* p = (const bf16x8*)
                (hsb + (r0 + rt * 16 + m) * HID + q * 32 + quad * 8);
            bfrag[rt][q] = __builtin_nontemporal_load(p);   // single-use rows
        }
    }

    for (int ct2 = 0; ct2 < 16; ct2++) {
        const int ct0 = 2 * ct2;
        f32x4 acc00 = {0.f, 0.f, 0.f, 0.f};
        f32x4 acc01 = {0.f, 0.f, 0.f, 0.f};
        f32x4 acc10 = {0.f, 0.f, 0.f, 0.f};
        f32x4 acc11 = {0.f, 0.f, 0.f, 0.f};
        #pragma unroll
        for (int q = 0; q < 4; q++) {
            bf16x8 aw0 = *(const bf16x8*)(wfrag + (((ct0)     * 4 + q) * 64 + lane) * 8);
            bf16x8 aw1 = *(const bf16x8*)(wfrag + (((ct0 + 1) * 4 + q) * 64 + lane) * 8);
            acc00 = __builtin_amdgcn_mfma_f32_16x16x32_bf16(aw0, bfrag[0][q], acc00, 0, 0, 0);
            acc01 = __builtin_amdgcn_mfma_f32_16x16x32_bf16(aw1, bfrag[0][q], acc01, 0, 0, 0);
            acc10 = __builtin_amdgcn_mfma_f32_16x16x32_bf16(aw0, bfrag[1][q], acc10, 0, 0, 0);
            acc11 = __builtin_amdgcn_mfma_f32_16x16x32_bf16(aw1, bfrag[1][q], acc11, 0, 0, 0);
        }
        const int n0 = ct0 * 16 + quad * 4;
        const f32x4 bias0 = *(const f32x4*)&fc_b[n0];
        const f32x4 bias1 = *(const f32x4*)&fc_b[n0 + 16];
        float* row0 = &out[(r0 + m) * NOUT];
        float* row1 = &out[(r0 + 16 + m) * NOUT];
        f32x4 o;
        o = acc00 + bias0;
        __builtin_nontemporal_store(o, (f32x4*)&row0[n0]);
        o = acc01 + bias1;
        __builtin_nontemporal_store(o, (f32x4*)&row0[n0 + 16]);
        o = acc10 + bias0;
        __builtin_nontemporal_store(o, (f32x4*)&row1[n0]);
        o = acc11 + bias1;
        __builtin_nontemporal_store(o, (f32x4*)&row1[n0 + 16]);
    }
}

extern "C" void kernel_launch(void* const* d_in, const int* in_sizes, int n_in,
                              void* d_out, int out_size, void* d_ws, size_t ws_size,
                              hipStream_t stream) {
    const float* latent = (const float*)d_in[0];   // (64,128)
    const float* W_hh   = (const float*)d_in[1];   // (384,128)
    const float* b_ih   = (const float*)d_in[2];   // (384,)
    const float* b_hh   = (const float*)d_in[3];   // (384,)
    const float* fc_W   = (const float*)d_in[4];   // (512,128)
    const float* fc_b   = (const float*)d_in[5];   // (512,)
    float* out = (float*)d_out;                    // (64,2048,512)

    __hip_bfloat16* hsb   = (__hip_bfloat16*)d_ws;                   // 33.5 MB
    __hip_bfloat16* wfrag = (__hip_bfloat16*)((char*)d_ws + (size_t)BATCH * SEQ * HID * 2);

    wprep<<<256, 256, 0, stream>>>(fc_W, wfrag);
    gru_seq<<<8, 512, 0, stream>>>(latent, W_hh, b_ih, b_hh, hsb);

    const int M = BATCH * SEQ;                     // 131072
    proj_mfma<<<M / 128, 256, 0, stream>>>(hsb, wfrag, fc_b, out);
}

// Round 10
// 1176.681 us; speedup vs baseline: 1.8128x; 1.0553x over previous
//
#include <hip/hip_runtime.h>
#include <hip/hip_bf16.h>

#define HID 128
#define SEQ 2048
#define BATCH 64
#define NOUT 512

typedef __attribute__((ext_vector_type(8))) short bf16x8;
typedef __attribute__((ext_vector_type(4))) float f32x4;

__device__ __forceinline__ short f2bf(float f) {
    unsigned u = __float_as_uint(f);
    unsigned r = u + 0x7fffu + ((u >> 16) & 1u);   // RNE
    return (short)(r >> 16);
}

// Hardware reciprocal: verified round 9 (gru 1380->937us, VALU theory
// confirmed). ~1ulp@2^-22 error, far below bf16 quantization.
__device__ __forceinline__ float fast_rcp(float x) {
    float y;
    asm("v_rcp_f32 %0, %1" : "=v"(y) : "v"(x));
    return y;
}

__device__ __forceinline__ float fast_sigmoid(float x) {
    return fast_rcp(1.0f + __expf(-x));
}

__device__ __forceinline__ float fast_tanh(float x) {
    return 1.0f - 2.0f * fast_rcp(__expf(2.0f * x) + 1.0f);
}

// Rebalance select in ONE instruction: lanes 8-15 of each 16-group (banks
// 2,3) take lane^8's `hiv` via ROW_ROR:8; lanes 0-7 (banks 0,1, masked off)
// keep `lo`. Replaces the round-9 DPP + v_cndmask pair (6 VALU saved, chain
// shortened) -- bank_mask granularity (4 lanes) aligns exactly with the
// hi = lane&8 split.
__device__ __forceinline__ float dpp_sel8(float lo, float hiv) {
    int y = __builtin_amdgcn_update_dpp(__builtin_bit_cast(int, lo),
                                        __builtin_bit_cast(int, hiv),
                                        0x128, 0xF, 0xC, false);
    return __builtin_bit_cast(float, y);
}

// One MFMA A-fragment from an f32 [rows][128] matrix:
// lane holds rows[row][kcol..kcol+7] as bf16x8.
__device__ __forceinline__ bf16x8 load_wfrag(const float* __restrict__ W,
                                             int row, int kcol) {
    const float* wp = W + (size_t)row * HID + kcol;
    float4 x = *(const float4*)wp;
    float4 y = *(const float4*)(wp + 4);
    bf16x8 f;
    f[0] = f2bf(x.x); f[1] = f2bf(x.y); f[2] = f2bf(x.z); f[3] = f2bf(x.w);
    f[4] = f2bf(y.x); f[5] = f2bf(y.y); f[6] = f2bf(y.z); f[7] = f2bf(y.w);
    return f;
}

// ---------------------------------------------------------------------------
// MFMA GRU recurrence. 8 blocks x 8 batches; 512 threads = 8 waves.
// Structural note (round 9/10 analysis): the per-block [16x384x128] gate
// GEMM is exactly 96 16x16x32 MFMAs = ~466 cyc/step of matrix-pipe time
// per CU -- IRREDUCIBLE by wave count / batch packing / CU spreading
// (n-split would need per-step cross-CU sync). Optimization surface is the
// ~630cyc of chain+issue overhead on top. Round-10 cuts (all issue/chain):
//   1. dpp_sel8: rebalance DPP+cndmask merged into one bank-masked DPP
//   2. v_cvt_pk_bf16_f32: manual f2bf pack (12 VALU) -> 1 instruction
//   3. hn = fma(z, hold-n, n): one op + one chain step shorter
// ---------------------------------------------------------------------------
__global__ __launch_bounds__(512, 1) void gru_seq(
    const float* __restrict__ latent,   // [BATCH][HID]
    const float* __restrict__ W_hh,     // [3*HID][HID]
    const float* __restrict__ b_ih,     // [3*HID]
    const float* __restrict__ b_hh,     // [3*HID]
    __hip_bfloat16* __restrict__ hs)    // [BATCH][SEQ][HID]  (bf16)
{
    const int tid  = threadIdx.x;          // 0..511
    const int j    = tid >> 6;             // wave 0..7 -> n-tiles {j,j+8,j+16}
    const int lane = tid & 63;
    const int rr   = lane & 15;            // operand 16-axis / D batch col
    const int g    = lane >> 4;            // 0..3
    const int hi   = (lane >> 3) & 1;      // upper half of 16-group
    const int br   = rr & 7;               // batch row 0..7
    const int h0   = 16 * j + 4 * g + 2 * hi;  // this lane's 2 h columns
    const int n0l  = 16 * j + 4 * g;           // this lane's 4 gate rows

    // [2 buffers][16 rows][128 cols] bf16, 16B-block swizzled within rows
    __shared__ __align__(16) __hip_bfloat16 Hl[2][2048];

    // ---- W fragments: 12 named registers ----
    const int wrow = j * 16 + rr;
    bf16x8 wr0 = load_wfrag(W_hh, wrow,       0 * 32 + g * 8);
    bf16x8 wr1 = load_wfrag(W_hh, wrow,       1 * 32 + g * 8);
    bf16x8 wr2 = load_wfrag(W_hh, wrow,       2 * 32 + g * 8);
    bf16x8 wr3 = load_wfrag(W_hh, wrow,       3 * 32 + g * 8);
    bf16x8 wz0 = load_wfrag(W_hh, wrow + 128, 0 * 32 + g * 8);
    bf16x8 wz1 = load_wfrag(W_hh, wrow + 128, 1 * 32 + g * 8);
    bf16x8 wz2 = load_wfrag(W_hh, wrow + 128, 2 * 32 + g * 8);
    bf16x8 wz3 = load_wfrag(W_hh, wrow + 128, 3 * 32 + g * 8);
    bf16x8 wn0 = load_wfrag(W_hh, wrow + 256, 0 * 32 + g * 8);
    bf16x8 wn1 = load_wfrag(W_hh, wrow + 256, 1 * 32 + g * 8);
    bf16x8 wn2 = load_wfrag(W_hh, wrow + 256, 2 * 32 + g * 8);
    bf16x8 wn3 = load_wfrag(W_hh, wrow + 256, 3 * 32 + g * 8);

    // ---- accumulator bias seeds (lane's 4 gate rows n0l..n0l+3) ----
    f32x4 seedR, seedZ, seedN;
    {
        float4 bi = *(const float4*)&b_ih[n0l];
        float4 bh = *(const float4*)&b_hh[n0l];
        seedR[0] = bi.x + bh.x; seedR[1] = bi.y + bh.y;
        seedR[2] = bi.z + bh.z; seedR[3] = bi.w + bh.w;
        bi = *(const float4*)&b_ih[HID + n0l];
        bh = *(const float4*)&b_hh[HID + n0l];
        seedZ[0] = bi.x + bh.x; seedZ[1] = bi.y + bh.y;
        seedZ[2] = bi.z + bh.z; seedZ[3] = bi.w + bh.w;
        bh = *(const float4*)&b_hh[2 * HID + n0l];
        seedN[0] = bh.x; seedN[1] = bh.y; seedN[2] = bh.z; seedN[3] = bh.w;
    }
    const float2 bin2 = *(const float2*)&b_ih[2 * HID + h0];
    const float bn0 = bin2.x, bn1 = bin2.y;

    // ---- swizzled LDS element offsets (round-4-proven) ----
    const int re0 = rr * 128 + (((0 * 4 + g) ^ (rr & 7)) << 3);
    const int re1 = rr * 128 + (((1 * 4 + g) ^ (rr & 7)) << 3);
    const int re2 = rr * 128 + (((2 * 4 + g) ^ (rr & 7)) << 3);
    const int re3 = rr * 128 + (((3 * 4 + g) ^ (rr & 7)) << 3);
    const int we = br * 128 + ((((2 * j) + (g >> 1)) ^ br) << 3)
                 + 4 * (g & 1) + 2 * hi;

    // ---- init: hold regs + H buffer 0 ----
    const int batch = blockIdx.x * 8 + br;
    float2 h02 = *(const float2*)&latent[batch * HID + h0];
    float hold0 = h02.x, hold1 = h02.y;
    {
        unsigned v = (unsigned short)f2bf(hold0)
                   | ((unsigned)(unsigned short)f2bf(hold1) << 16);
        *(unsigned*)&Hl[0][we] = v;
    }
    __syncthreads();

    __hip_bfloat16* op = hs + ((size_t)batch * SEQ) * HID + h0;

    bf16x8 hf0 = {}, hf1 = {}, hf2 = {}, hf3 = {};
    int p = 0;
    for (int t = 0; t < SEQ; t++) {
        // H fragments: rows 0-7 only (rr>=8 lanes feed discarded D columns)
        const __hip_bfloat16* hb = &Hl[p][0];
        if (rr < 8) {
            hf0 = *(const bf16x8*)&hb[re0];
            hf1 = *(const bf16x8*)&hb[re1];
            hf2 = *(const bf16x8*)&hb[re2];
            hf3 = *(const bf16x8*)&hb[re3];
        }

        f32x4 a0 = seedR;   // r-gate tile j      (bias pre-seeded)
        f32x4 a1 = seedZ;   // z-gate tile j+8
        f32x4 a2 = seedN;   // n-gate tile j+16   (b_hh part)
        __builtin_amdgcn_s_setprio(1);
        a0 = __builtin_amdgcn_mfma_f32_16x16x32_bf16(wr0, hf0, a0, 0, 0, 0);
        a1 = __builtin_amdgcn_mfma_f32_16x16x32_bf16(wz0, hf0, a1, 0, 0, 0);
        a2 = __builtin_amdgcn_mfma_f32_16x16x32_bf16(wn0, hf0, a2, 0, 0, 0);
        a0 = __builtin_amdgcn_mfma_f32_16x16x32_bf16(wr1, hf1, a0, 0, 0, 0);
        a1 = __builtin_amdgcn_mfma_f32_16x16x32_bf16(wz1, hf1, a1, 0, 0, 0);
        a2 = __builtin_amdgcn_mfma_f32_16x16x32_bf16(wn1, hf1, a2, 0, 0, 0);
        a0 = __builtin_amdgcn_mfma_f32_16x16x32_bf16(wr2, hf2, a0, 0, 0, 0);
        a1 = __builtin_amdgcn_mfma_f32_16x16x32_bf16(wz2, hf2, a1, 0, 0, 0);
        a2 = __builtin_amdgcn_mfma_f32_16x16x32_bf16(wn2, hf2, a2, 0, 0, 0);
        a0 = __builtin_amdgcn_mfma_f32_16x16x32_bf16(wr3, hf3, a0, 0, 0, 0);
        a1 = __builtin_amdgcn_mfma_f32_16x16x32_bf16(wz3, hf3, a1, 0, 0, 0);
        a2 = __builtin_amdgcn_mfma_f32_16x16x32_bf16(wn3, hf3, a2, 0, 0, 0);
        __builtin_amdgcn_s_setprio(0);

        // rebalance + select fused: one bank-masked DPP per gate value
        float gr0 = dpp_sel8(a0[0], a0[2]), gr1 = dpp_sel8(a0[1], a0[3]);
        float gz0 = dpp_sel8(a1[0], a1[2]), gz1 = dpp_sel8(a1[1], a1[3]);
        float gn0 = dpp_sel8(a2[0], a2[2]), gn1 = dpp_sel8(a2[1], a2[3]);

        // activations (biases pre-folded into accumulators)
        float r0 = fast_sigmoid(gr0);
        float z0 = fast_sigmoid(gz0);
        float n0 = fast_tanh(bn0 + r0 * gn0);
        float hn0 = fmaf(z0, hold0 - n0, n0);
        hold0 = hn0;
        float r1 = fast_sigmoid(gr1);
        float z1 = fast_sigmoid(gz1);
        float n1 = fast_tanh(bn1 + r1 * gn1);
        float hn1 = fmaf(z1, hold1 - n1, n1);
        hold1 = hn1;

        // pack both h values to bf16 in ONE instruction (RNE on gfx950)
        unsigned v;
        asm("v_cvt_pk_bf16_f32 %0, %1, %2" : "=v"(v) : "v"(hn0), "v"(hn1));
        *(unsigned*)&Hl[p ^ 1][we] = v;    // next step's H (swizzled slot)
        *(unsigned*)op = v;                // history output (not drained)
        op += HID;

        // LDS-only drain + raw barrier: global stores stay in flight
        asm volatile("s_waitcnt lgkmcnt(0)" ::: "memory");
        __builtin_amdgcn_s_barrier();
        asm volatile("" ::: "memory");
        p ^= 1;
    }
}

// ---------------------------------------------------------------------------
// Repack fc_W (f32 [512][128]) into bf16 MFMA fragment order:
//   wfrag[((ct*4 + q)*64 + lane)*8 + j] = bf16(fc_W[ct*16 + (lane&15)]
//                                                  [q*32 + (lane>>4)*8 + j])
// ---------------------------------------------------------------------------
__global__ void wprep(const float* __restrict__ fc_W,
                      __hip_bfloat16* __restrict__ wfrag)
{
    int t = blockIdx.x * 256 + threadIdx.x;      // 0..65535
    int j    = t & 7;
    int lane = (t >> 3) & 63;
    int q    = (t >> 9) & 3;
    int ct   = t >> 11;
    int n = ct * 16 + (lane & 15);
    int k = q * 32 + (lane >> 4) * 8 + j;
    unsigned short v = (unsigned short)f2bf(fc_W[n * HID + k]);
    wfrag[t] = __builtin_bit_cast(__hip_bfloat16, v);
}

// ---------------------------------------------------------------------------
// Projection: out[row][o] = sum_k hs[row][k] * fc_W[o][k] + fc_b[o]
// M = 131072, N = 512, K = 128. bf16 MFMA 16x16x32, operand-swapped.
// Nontemporal stores/loads. ~84us after the ~218us fixed harness overhead
// (round-8 discovery) -- near the write roofline.
// ---------------------------------------------------------------------------
__global__ __launch_bounds__(256) void proj_mfma(
    const __hip_bfloat16* __restrict__ hsb,    // [M][128] bf16
    const __hip_bfloat16* __restrict__ wfrag,  // fragment-ordered [32][4][64][8]
    const float* __restrict__ fc_b,            // [512]
    float* __restrict__ out)                   // [M][512] f32
{
    const int lane = threadIdx.x & 63;
    const int wave = threadIdx.x >> 6;
    const int m    = lane & 15;
    const int quad = lane >> 4;

    const long r0 = ((long)blockIdx.x * 4 + wave) * 32;

    bf16x8 bfrag[2][4];                         // hs rows as second operand
    #pragma unroll
    for (int rt = 0; rt < 2; rt++) {
        #pragma unroll
        for (int q = 0; q < 4; q++) {
            const bf16x8* p = (const bf16x8*)
                (hsb + (r0 + rt * 16 + m) * HID + q * 32 + quad * 8);
            bfrag[rt][q] = __builtin_nontemporal_load(p);   // single-use rows
        }
    }

    for (int ct2 = 0; ct2 < 16; ct2++) {
        const int ct0 = 2 * ct2;
        f32x4 acc00 = {0.f, 0.f, 0.f, 0.f};
        f32x4 acc01 = {0.f, 0.f, 0.f, 0.f};
        f32x4 acc10 = {0.f, 0.f, 0.f, 0.f};
        f32x4 acc11 = {0.f, 0.f, 0.f, 0.f};
        #pragma unroll
        for (int q = 0; q < 4; q++) {
            bf16x8 aw0 = *(const bf16x8*)(wfrag + (((ct0)     * 4 + q) * 64 + lane) * 8);
            bf16x8 aw1 = *(const bf16x8*)(wfrag + (((ct0 + 1) * 4 + q) * 64 + lane) * 8);
            acc00 = __builtin_amdgcn_mfma_f32_16x16x32_bf16(aw0, bfrag[0][q], acc00, 0, 0, 0);
            acc01 = __builtin_amdgcn_mfma_f32_16x16x32_bf16(aw1, bfrag[0][q], acc01, 0, 0, 0);
            acc10 = __builtin_amdgcn_mfma_f32_16x16x32_bf16(aw0, bfrag[1][q], acc10, 0, 0, 0);
            acc11 = __builtin_amdgcn_mfma_f32_16x16x32_bf16(aw1, bfrag[1][q], acc11, 0, 0, 0);
        }
        const int n0 = ct0 * 16 + quad * 4;
        const f32x4 bias0 = *(const f32x4*)&fc_b[n0];
        const f32x4 bias1 = *(const f32x4*)&fc_b[n0 + 16];
        float* row0 = &out[(r0 + m) * NOUT];
        float* row1 = &out[(r0 + 16 + m) * NOUT];
        f32x4 o;
        o = acc00 + bias0;
        __builtin_nontemporal_store(o, (f32x4*)&row0[n0]);
        o = acc01 + bias1;
        __builtin_nontemporal_store(o, (f32x4*)&row0[n0 + 16]);
        o = acc10 + bias0;
        __builtin_nontemporal_store(o, (f32x4*)&row1[n0]);
        o = acc11 + bias1;
        __builtin_nontemporal_store(o, (f32x4*)&row1[n0 + 16]);
    }
}

extern "C" void kernel_launch(void* const* d_in, const int* in_sizes, int n_in,
                              void* d_out, int out_size, void* d_ws, size_t ws_size,
                              hipStream_t stream) {
    const float* latent = (const float*)d_in[0];   // (64,128)
    const float* W_hh   = (const float*)d_in[1];   // (384,128)
    const float* b_ih   = (const float*)d_in[2];   // (384,)
    const float* b_hh   = (const float*)d_in[3];   // (384,)
    const float* fc_W   = (const float*)d_in[4];   // (512,128)
    const float* fc_b   = (const float*)d_in[5];   // (512,)
    float* out = (float*)d_out;                    // (64,2048,512)

    __hip_bfloat16* hsb   = (__hip_bfloat16*)d_ws;                   // 33.5 MB
    __hip_bfloat16* wfrag = (__hip_bfloat16*)((char*)d_ws + (size_t)BATCH * SEQ * HID * 2);

    wprep<<<256, 256, 0, stream>>>(fc_W, wfrag);
    gru_seq<<<8, 512, 0, stream>>>(latent, W_hh, b_ih, b_hh, hsb);

    const int M = BATCH * SEQ;                     // 131072
    proj_mfma<<<M / 128, 256, 0, stream>>>(hsb, wfrag, fc_b, out);
}

// Round 11
// 1119.719 us; speedup vs baseline: 1.9050x; 1.0509x over previous
//
#include <hip/hip_runtime.h>
#include <hip/hip_bf16.h>

#define HID 128
#define SEQ 2048
#define BATCH 64
#define NOUT 512

typedef __attribute__((ext_vector_type(8))) short bf16x8;
typedef __attribute__((ext_vector_type(4))) float f32x4;

__device__ __forceinline__ short f2bf(float f) {
    unsigned u = __float_as_uint(f);
    unsigned r = u + 0x7fffu + ((u >> 16) & 1u);   // RNE
    return (short)(r >> 16);
}

// Hardware reciprocal: verified round 9 (gru 1380->937us). ~2^-22 error.
__device__ __forceinline__ float fast_rcp(float x) {
    float y;
    asm("v_rcp_f32 %0, %1" : "=v"(y) : "v"(x));
    return y;
}

// v_exp_f32 IS exp2 on AMD. The log2e/2log2e factors are pre-folded into
// the bf16 W fragments + accumulator seeds (linear pre-activations), so
// the activation chain has ZERO multiplies left:
//   sigmoid(a) -> rcp(1 + exp2(-x')),  x' = log2e * a   (neg = free modifier)
//   tanh(a)    -> 1 - 2*rcp(exp2(y') + 1),  y' = 2*log2e * a
__device__ __forceinline__ float exp2_neg(float x) {   // 2^(-x)
    float y;
    asm("v_exp_f32 %0, -%1" : "=v"(y) : "v"(x));
    return y;
}
__device__ __forceinline__ float exp2_pos(float x) {   // 2^x
    float y;
    asm("v_exp_f32 %0, %1" : "=v"(y) : "v"(x));
    return y;
}
__device__ __forceinline__ float sigmoid_pre(float xp) {   // xp = log2e*a
    return fast_rcp(1.0f + exp2_neg(xp));
}
__device__ __forceinline__ float tanh_pre(float yp) {      // yp = 2log2e*a
    return fmaf(-2.0f, fast_rcp(exp2_pos(yp) + 1.0f), 1.0f);
}

#define LOG2E 1.4426950408889634f

// Rebalance select in ONE bank-masked DPP (verified round 10):
// lanes 8-15 of each 16-group (banks 2,3) take lane^8's `hiv` via
// ROW_ROR:8; lanes 0-7 keep `lo`.
__device__ __forceinline__ float dpp_sel8(float lo, float hiv) {
    int y = __builtin_amdgcn_update_dpp(__builtin_bit_cast(int, lo),
                                        __builtin_bit_cast(int, hiv),
                                        0x128, 0xF, 0xC, false);
    return __builtin_bit_cast(float, y);
}

// One MFMA A-fragment from an f32 [rows][128] matrix, scaled then
// RNE-rounded to bf16 (scale folds exp2 constants; relative quantization
// error unchanged).
__device__ __forceinline__ bf16x8 load_wfrag(const float* __restrict__ W,
                                             int row, int kcol, float scale) {
    const float* wp = W + (size_t)row * HID + kcol;
    float4 x = *(const float4*)wp;
    float4 y = *(const float4*)(wp + 4);
    bf16x8 f;
    f[0] = f2bf(x.x * scale); f[1] = f2bf(x.y * scale);
    f[2] = f2bf(x.z * scale); f[3] = f2bf(x.w * scale);
    f[4] = f2bf(y.x * scale); f[5] = f2bf(y.y * scale);
    f[6] = f2bf(y.z * scale); f[7] = f2bf(y.w * scale);
    return f;
}

// ---------------------------------------------------------------------------
// MFMA GRU recurrence. 8 blocks x 8 batches; 512 threads = 8 waves.
// Cost model (round-10 verified): step ~1025cyc = MFMA floor 466 (96 16x16x32
// per block-step, irreducible for this decomposition) + LDS exchange ~250
// + activation chain ~150 + residual VALU ~150. Round-11: exp2 prescaling
// removes the last 3 muls from the serial r->n->h chain and ~8 VALU/thread.
// ---------------------------------------------------------------------------
__global__ __launch_bounds__(512, 1) void gru_seq(
    const float* __restrict__ latent,   // [BATCH][HID]
    const float* __restrict__ W_hh,     // [3*HID][HID]
    const float* __restrict__ b_ih,     // [3*HID]
    const float* __restrict__ b_hh,     // [3*HID]
    __hip_bfloat16* __restrict__ hs)    // [BATCH][SEQ][HID]  (bf16)
{
    const int tid  = threadIdx.x;          // 0..511
    const int j    = tid >> 6;             // wave 0..7 -> n-tiles {j,j+8,j+16}
    const int lane = tid & 63;
    const int rr   = lane & 15;            // operand 16-axis / D batch col
    const int g    = lane >> 4;            // 0..3
    const int hi   = (lane >> 3) & 1;      // upper half of 16-group
    const int br   = rr & 7;               // batch row 0..7
    const int h0   = 16 * j + 4 * g + 2 * hi;  // this lane's 2 h columns
    const int n0l  = 16 * j + 4 * g;           // this lane's 4 gate rows

    // [2 buffers][16 rows][128 cols] bf16, 16B-block swizzled within rows
    __shared__ __align__(16) __hip_bfloat16 Hl[2][2048];

    // ---- W fragments: 12 named registers; r/z scaled log2e, n by 2log2e ----
    const int wrow = j * 16 + rr;
    bf16x8 wr0 = load_wfrag(W_hh, wrow,       0 * 32 + g * 8, LOG2E);
    bf16x8 wr1 = load_wfrag(W_hh, wrow,       1 * 32 + g * 8, LOG2E);
    bf16x8 wr2 = load_wfrag(W_hh, wrow,       2 * 32 + g * 8, LOG2E);
    bf16x8 wr3 = load_wfrag(W_hh, wrow,       3 * 32 + g * 8, LOG2E);
    bf16x8 wz0 = load_wfrag(W_hh, wrow + 128, 0 * 32 + g * 8, LOG2E);
    bf16x8 wz1 = load_wfrag(W_hh, wrow + 128, 1 * 32 + g * 8, LOG2E);
    bf16x8 wz2 = load_wfrag(W_hh, wrow + 128, 2 * 32 + g * 8, LOG2E);
    bf16x8 wz3 = load_wfrag(W_hh, wrow + 128, 3 * 32 + g * 8, LOG2E);
    bf16x8 wn0 = load_wfrag(W_hh, wrow + 256, 0 * 32 + g * 8, 2.0f * LOG2E);
    bf16x8 wn1 = load_wfrag(W_hh, wrow + 256, 1 * 32 + g * 8, 2.0f * LOG2E);
    bf16x8 wn2 = load_wfrag(W_hh, wrow + 256, 2 * 32 + g * 8, 2.0f * LOG2E);
    bf16x8 wn3 = load_wfrag(W_hh, wrow + 256, 3 * 32 + g * 8, 2.0f * LOG2E);

    // ---- accumulator bias seeds, matching scales ----
    f32x4 seedR, seedZ, seedN;
    {
        float4 bi = *(const float4*)&b_ih[n0l];
        float4 bh = *(const float4*)&b_hh[n0l];
        seedR[0] = (bi.x + bh.x) * LOG2E; seedR[1] = (bi.y + bh.y) * LOG2E;
        seedR[2] = (bi.z + bh.z) * LOG2E; seedR[3] = (bi.w + bh.w) * LOG2E;
        bi = *(const float4*)&b_ih[HID + n0l];
        bh = *(const float4*)&b_hh[HID + n0l];
        seedZ[0] = (bi.x + bh.x) * LOG2E; seedZ[1] = (bi.y + bh.y) * LOG2E;
        seedZ[2] = (bi.z + bh.z) * LOG2E; seedZ[3] = (bi.w + bh.w) * LOG2E;
        bh = *(const float4*)&b_hh[2 * HID + n0l];
        seedN[0] = bh.x * 2.0f * LOG2E; seedN[1] = bh.y * 2.0f * LOG2E;
        seedN[2] = bh.z * 2.0f * LOG2E; seedN[3] = bh.w * 2.0f * LOG2E;
    }
    const float2 bin2 = *(const float2*)&b_ih[2 * HID + h0];
    const float bn0 = bin2.x * 2.0f * LOG2E, bn1 = bin2.y * 2.0f * LOG2E;

    // ---- swizzled LDS element offsets (round-4-proven) ----
    const int re0 = rr * 128 + (((0 * 4 + g) ^ (rr & 7)) << 3);
    const int re1 = rr * 128 + (((1 * 4 + g) ^ (rr & 7)) << 3);
    const int re2 = rr * 128 + (((2 * 4 + g) ^ (rr & 7)) << 3);
    const int re3 = rr * 128 + (((3 * 4 + g) ^ (rr & 7)) << 3);
    const int we = br * 128 + ((((2 * j) + (g >> 1)) ^ br) << 3)
                 + 4 * (g & 1) + 2 * hi;

    // ---- init: hold regs + H buffer 0 ----
    const int batch = blockIdx.x * 8 + br;
    float2 h02 = *(const float2*)&latent[batch * HID + h0];
    float hold0 = h02.x, hold1 = h02.y;
    {
        unsigned v = (unsigned short)f2bf(hold0)
                   | ((unsigned)(unsigned short)f2bf(hold1) << 16);
        *(unsigned*)&Hl[0][we] = v;
    }
    __syncthreads();

    __hip_bfloat16* op = hs + ((size_t)batch * SEQ) * HID + h0;

    bf16x8 hf0 = {}, hf1 = {}, hf2 = {}, hf3 = {};
    int p = 0;
    for (int t = 0; t < SEQ; t++) {
        // H fragments: rows 0-7 only (rr>=8 lanes feed discarded D columns)
        const __hip_bfloat16* hb = &Hl[p][0];
        if (rr < 8) {
            hf0 = *(const bf16x8*)&hb[re0];
            hf1 = *(const bf16x8*)&hb[re1];
            hf2 = *(const bf16x8*)&hb[re2];
            hf3 = *(const bf16x8*)&hb[re3];
        }

        f32x4 a0 = seedR;   // r-gate tile j      (log2e-scaled domain)
        f32x4 a1 = seedZ;   // z-gate tile j+8
        f32x4 a2 = seedN;   // n-gate tile j+16   (2log2e-scaled domain)
        __builtin_amdgcn_s_setprio(1);
        a0 = __builtin_amdgcn_mfma_f32_16x16x32_bf16(wr0, hf0, a0, 0, 0, 0);
        a1 = __builtin_amdgcn_mfma_f32_16x16x32_bf16(wz0, hf0, a1, 0, 0, 0);
        a2 = __builtin_amdgcn_mfma_f32_16x16x32_bf16(wn0, hf0, a2, 0, 0, 0);
        a0 = __builtin_amdgcn_mfma_f32_16x16x32_bf16(wr1, hf1, a0, 0, 0, 0);
        a1 = __builtin_amdgcn_mfma_f32_16x16x32_bf16(wz1, hf1, a1, 0, 0, 0);
        a2 = __builtin_amdgcn_mfma_f32_16x16x32_bf16(wn1, hf1, a2, 0, 0, 0);
        a0 = __builtin_amdgcn_mfma_f32_16x16x32_bf16(wr2, hf2, a0, 0, 0, 0);
        a1 = __builtin_amdgcn_mfma_f32_16x16x32_bf16(wz2, hf2, a1, 0, 0, 0);
        a2 = __builtin_amdgcn_mfma_f32_16x16x32_bf16(wn2, hf2, a2, 0, 0, 0);
        a0 = __builtin_amdgcn_mfma_f32_16x16x32_bf16(wr3, hf3, a0, 0, 0, 0);
        a1 = __builtin_amdgcn_mfma_f32_16x16x32_bf16(wz3, hf3, a1, 0, 0, 0);
        a2 = __builtin_amdgcn_mfma_f32_16x16x32_bf16(wn3, hf3, a2, 0, 0, 0);
        __builtin_amdgcn_s_setprio(0);

        // rebalance + select fused: one bank-masked DPP per gate value
        float gr0 = dpp_sel8(a0[0], a0[2]), gr1 = dpp_sel8(a0[1], a0[3]);
        float gz0 = dpp_sel8(a1[0], a1[2]), gz1 = dpp_sel8(a1[1], a1[3]);
        float gn0 = dpp_sel8(a2[0], a2[2]), gn1 = dpp_sel8(a2[1], a2[3]);

        // activations: zero multiplies left (scales pre-folded)
        float r0 = sigmoid_pre(gr0);
        float z0 = sigmoid_pre(gz0);
        float n0 = tanh_pre(fmaf(r0, gn0, bn0));
        float hn0 = fmaf(z0, hold0 - n0, n0);
        hold0 = hn0;
        float r1 = sigmoid_pre(gr1);
        float z1 = sigmoid_pre(gz1);
        float n1 = tanh_pre(fmaf(r1, gn1, bn1));
        float hn1 = fmaf(z1, hold1 - n1, n1);
        hold1 = hn1;

        // pack both h values to bf16 in ONE instruction (RNE on gfx950)
        unsigned v;
        asm("v_cvt_pk_bf16_f32 %0, %1, %2" : "=v"(v) : "v"(hn0), "v"(hn1));
        *(unsigned*)&Hl[p ^ 1][we] = v;    // next step's H (swizzled slot)
        *(unsigned*)op = v;                // history output (not drained)
        op += HID;

        // LDS-only drain + raw barrier: global stores stay in flight
        asm volatile("s_waitcnt lgkmcnt(0)" ::: "memory");
        __builtin_amdgcn_s_barrier();
        asm volatile("" ::: "memory");
        p ^= 1;
    }
}

// ---------------------------------------------------------------------------
// Repack fc_W (f32 [512][128]) into bf16 MFMA fragment order:
//   wfrag[((ct*4 + q)*64 + lane)*8 + j] = bf16(fc_W[ct*16 + (lane&15)]
//                                                  [q*32 + (lane>>4)*8 + j])
// ---------------------------------------------------------------------------
__global__ void wprep(const float* __restrict__ fc_W,
                      __hip_bfloat16* __restrict__ wfrag)
{
    int t = blockIdx.x * 256 + threadIdx.x;      // 0..65535
    int j    = t & 7;
    int lane = (t >> 3) & 63;
    int q    = (t >> 9) & 3;
    int ct   = t >> 11;
    int n = ct * 16 + (lane & 15);
    int k = q * 32 + (lane >> 4) * 8 + j;
    unsigned short v = (unsigned short)f2bf(fc_W[n * HID + k]);
    wfrag[t] = __builtin_bit_cast(__hip_bfloat16, v);
}

// ---------------------------------------------------------------------------
// Projection: out[row][o] = sum_k hs[row][k] * fc_W[o][k] + fc_b[o]
// M = 131072, N = 512, K = 128. bf16 MFMA 16x16x32, operand-swapped.
// Nontemporal stores/loads. ~84us after the ~218us fixed harness overhead
// (round-8 discovery) -- near the write roofline.
// ---------------------------------------------------------------------------
__global__ __launch_bounds__(256) void proj_mfma(
    const __hip_bfloat16* __restrict__ hsb,    // [M][128] bf16
    const __hip_bfloat16* __restrict__ wfrag,  // fragment-ordered [32][4][64][8]
    const float* __restrict__ fc_b,            // [512]
    float* __restrict__ out)                   // [M][512] f32
{
    const int lane = threadIdx.x & 63;
    const int wave = threadIdx.x >> 6;
    const int m    = lane & 15;
    const int quad = lane >> 4;

    const long r0 = ((long)blockIdx.x * 4 + wave) * 32;

    bf16x8 bfrag[2][4];                         // hs rows as second operand
    #pragma unroll
    for (int rt = 0; rt < 2; rt++) {
        #pragma unroll
        for (int q = 0; q < 4; q++) {
            const bf16x8* p = (const bf16x8*)
                (hsb + (r0 + rt * 16 + m) * HID + q * 32 + quad * 8);
            bfrag[rt][q] = __builtin_nontemporal_load(p);   // single-use rows
        }
    }

    for (int ct2 = 0; ct2 < 16; ct2++) {
        const int ct0 = 2 * ct2;
        f32x4 acc00 = {0.f, 0.f, 0.f, 0.f};
        f32x4 acc01 = {0.f, 0.f, 0.f, 0.f};
        f32x4 acc10 = {0.f, 0.f, 0.f, 0.f};
        f32x4 acc11 = {0.f, 0.f, 0.f, 0.f};
        #pragma unroll
        for (int q = 0; q < 4; q++) {
            bf16x8 aw0 = *(const bf16x8*)(wfrag + (((ct0)     * 4 + q) * 64 + lane) * 8);
            bf16x8 aw1 = *(const bf16x8*)(wfrag + (((ct0 + 1) * 4 + q) * 64 + lane) * 8);
            acc00 = __builtin_amdgcn_mfma_f32_16x16x32_bf16(aw0, bfrag[0][q], acc00, 0, 0, 0);
            acc01 = __builtin_amdgcn_mfma_f32_16x16x32_bf16(aw1, bfrag[0][q], acc01, 0, 0, 0);
            acc10 = __builtin_amdgcn_mfma_f32_16x16x32_bf16(aw0, bfrag[1][q], acc10, 0, 0, 0);
            acc11 = __builtin_amdgcn_mfma_f32_16x16x32_bf16(aw1, bfrag[1][q], acc11, 0, 0, 0);
        }
        const int n0 = ct0 * 16 + quad * 4;
        const f32x4 bias0 = *(const f32x4*)&fc_b[n0];
        const f32x4 bias1 = *(const f32x4*)&fc_b[n0 + 16];
        float* row0 = &out[(r0 + m) * NOUT];
        float* row1 = &out[(r0 + 16 + m) * NOUT];
        f32x4 o;
        o = acc00 + bias0;
        __builtin_nontemporal_store(o, (f32x4*)&row0[n0]);
        o = acc01 + bias1;
        __builtin_nontemporal_store(o, (f32x4*)&row0[n0 + 16]);
        o = acc10 + bias0;
        __builtin_nontemporal_store(o, (f32x4*)&row1[n0]);
        o = acc11 + bias1;
        __builtin_nontemporal_store(o, (f32x4*)&row1[n0 + 16]);
    }
}

extern "C" void kernel_launch(void* const* d_in, const int* in_sizes, int n_in,
                              void* d_out, int out_size, void* d_ws, size_t ws_size,
                              hipStream_t stream) {
    const float* latent = (const float*)d_in[0];   // (64,128)
    const float* W_hh   = (const float*)d_in[1];   // (384,128)
    const float* b_ih   = (const float*)d_in[2];   // (384,)
    const float* b_hh   = (const float*)d_in[3];   // (384,)
    const float* fc_W   = (const float*)d_in[4];   // (512,128)
    const float* fc_b   = (const float*)d_in[5];   // (512,)
    float* out = (float*)d_out;                    // (64,2048,512)

    __hip_bfloat16* hsb   = (__hip_bfloat16*)d_ws;                   // 33.5 MB
    __hip_bfloat16* wfrag = (__hip_bfloat16*)((char*)d_ws + (size_t)BATCH * SEQ * HID * 2);

    wprep<<<256, 256, 0, stream>>>(fc_W, wfrag);
    gru_seq<<<8, 512, 0, stream>>>(latent, W_hh, b_ih, b_hh, hsb);

    const int M = BATCH * SEQ;                     // 131072
    proj_mfma<<<M / 128, 256, 0, stream>>>(hsb, wfrag, fc_b, out);
}

// Round 12
// 1025.551 us; speedup vs baseline: 2.0799x; 1.0918x over previous
//
#include <hip/hip_runtime.h>
#include <hip/hip_bf16.h>

#define HID 128
#define SEQ 2048
#define BATCH 64
#define NOUT 512

typedef __attribute__((ext_vector_type(8))) short bf16x8;
typedef __attribute__((ext_vector_type(4))) float f32x4;

__device__ __forceinline__ short f2bf(float f) {
    unsigned u = __float_as_uint(f);
    unsigned r = u + 0x7fffu + ((u >> 16) & 1u);   // RNE
    return (short)(r >> 16);
}

// Hardware reciprocal: verified round 9 (gru 1380->937us). ~2^-22 error.
__device__ __forceinline__ float fast_rcp(float x) {
    float y;
    asm("v_rcp_f32 %0, %1" : "=v"(y) : "v"(x));
    return y;
}

// v_exp_f32 IS exp2 on AMD; log2e/2log2e pre-folded into W frags + seeds
// (verified round 11: 875->818us). Zero multiplies in the activation chain.
__device__ __forceinline__ float exp2_neg(float x) {   // 2^(-x)
    float y;
    asm("v_exp_f32 %0, -%1" : "=v"(y) : "v"(x));
    return y;
}
__device__ __forceinline__ float exp2_pos(float x) {   // 2^x
    float y;
    asm("v_exp_f32 %0, %1" : "=v"(y) : "v"(x));
    return y;
}
__device__ __forceinline__ float sigmoid_pre(float xp) {   // xp = log2e*a
    return fast_rcp(1.0f + exp2_neg(xp));
}
__device__ __forceinline__ float tanh_pre(float yp) {      // yp = 2log2e*a
    return fmaf(-2.0f, fast_rcp(exp2_pos(yp) + 1.0f), 1.0f);
}

#define LOG2E 1.4426950408889634f

// Rebalance select in ONE bank-masked DPP (verified round 10):
// lanes 8-15 of each 16-group (banks 2,3) take lane^8's `hiv` via
// ROW_ROR:8; lanes 0-7 keep `lo`.
__device__ __forceinline__ float dpp_sel8(float lo, float hiv) {
    int y = __builtin_amdgcn_update_dpp(__builtin_bit_cast(int, lo),
                                        __builtin_bit_cast(int, hiv),
                                        0x128, 0xF, 0xC, false);
    return __builtin_bit_cast(float, y);
}

// One MFMA A-fragment from an f32 [rows][128] matrix, scaled then
// RNE-rounded to bf16.
__device__ __forceinline__ bf16x8 load_wfrag(const float* __restrict__ W,
                                             int row, int kcol, float scale) {
    const float* wp = W + (size_t)row * HID + kcol;
    float4 x = *(const float4*)wp;
    float4 y = *(const float4*)(wp + 4);
    bf16x8 f;
    f[0] = f2bf(x.x * scale); f[1] = f2bf(x.y * scale);
    f[2] = f2bf(x.z * scale); f[3] = f2bf(x.w * scale);
    f[4] = f2bf(y.x * scale); f[5] = f2bf(y.y * scale);
    f[6] = f2bf(y.z * scale); f[7] = f2bf(y.w * scale);
    return f;
}

// ---------------------------------------------------------------------------
// MFMA GRU recurrence. 8 blocks x 8 batches; 512 threads = 8 waves.
// Cost model (round-11 verified, step = 959 cyc):
//   ds_read ~120 (post-barrier, unhideable) + matrix 466 (96 MFMA, floor)
//   + act chain ~130 + write/barrier ~70 = ~790 floor; ~170 bookkeeping.
// Round-12 (bookkeeping pass):
//   1. branchless aliased H reads -- lanes rr>=8 read the same addresses
//      as rr-8 (same-address broadcast is free); removes the exec-mask
//      toggle pair per step. Their hf feeds only discarded D cols 8-15.
//   2. unroll x2 with static Hl[0]/Hl[1] -- removes p^=1 and the dynamic
//      buffer-base computation per step.
// ---------------------------------------------------------------------------
__global__ __launch_bounds__(512, 1) void gru_seq(
    const float* __restrict__ latent,   // [BATCH][HID]
    const float* __restrict__ W_hh,     // [3*HID][HID]
    const float* __restrict__ b_ih,     // [3*HID]
    const float* __restrict__ b_hh,     // [3*HID]
    __hip_bfloat16* __restrict__ hs)    // [BATCH][SEQ][HID]  (bf16)
{
    const int tid  = threadIdx.x;          // 0..511
    const int j    = tid >> 6;             // wave 0..7 -> n-tiles {j,j+8,j+16}
    const int lane = tid & 63;
    const int rr   = lane & 15;            // operand 16-axis / D batch col
    const int g    = lane >> 4;            // 0..3
    const int hi   = (lane >> 3) & 1;      // upper half of 16-group
    const int br   = rr & 7;               // batch row 0..7
    const int h0   = 16 * j + 4 * g + 2 * hi;  // this lane's 2 h columns
    const int n0l  = 16 * j + 4 * g;           // this lane's 4 gate rows

    // [2 buffers][16 rows][128 cols] bf16, 16B-block swizzled within rows
    __shared__ __align__(16) __hip_bfloat16 Hl[2][2048];

    // ---- W fragments: 12 named registers; r/z scaled log2e, n by 2log2e ----
    const int wrow = j * 16 + rr;
    bf16x8 wr0 = load_wfrag(W_hh, wrow,       0 * 32 + g * 8, LOG2E);
    bf16x8 wr1 = load_wfrag(W_hh, wrow,       1 * 32 + g * 8, LOG2E);
    bf16x8 wr2 = load_wfrag(W_hh, wrow,       2 * 32 + g * 8, LOG2E);
    bf16x8 wr3 = load_wfrag(W_hh, wrow,       3 * 32 + g * 8, LOG2E);
    bf16x8 wz0 = load_wfrag(W_hh, wrow + 128, 0 * 32 + g * 8, LOG2E);
    bf16x8 wz1 = load_wfrag(W_hh, wrow + 128, 1 * 32 + g * 8, LOG2E);
    bf16x8 wz2 = load_wfrag(W_hh, wrow + 128, 2 * 32 + g * 8, LOG2E);
    bf16x8 wz3 = load_wfrag(W_hh, wrow + 128, 3 * 32 + g * 8, LOG2E);
    bf16x8 wn0 = load_wfrag(W_hh, wrow + 256, 0 * 32 + g * 8, 2.0f * LOG2E);
    bf16x8 wn1 = load_wfrag(W_hh, wrow + 256, 1 * 32 + g * 8, 2.0f * LOG2E);
    bf16x8 wn2 = load_wfrag(W_hh, wrow + 256, 2 * 32 + g * 8, 2.0f * LOG2E);
    bf16x8 wn3 = load_wfrag(W_hh, wrow + 256, 3 * 32 + g * 8, 2.0f * LOG2E);

    // ---- accumulator bias seeds, matching scales ----
    f32x4 seedR, seedZ, seedN;
    {
        float4 bi = *(const float4*)&b_ih[n0l];
        float4 bh = *(const float4*)&b_hh[n0l];
        seedR[0] = (bi.x + bh.x) * LOG2E; seedR[1] = (bi.y + bh.y) * LOG2E;
        seedR[2] = (bi.z + bh.z) * LOG2E; seedR[3] = (bi.w + bh.w) * LOG2E;
        bi = *(const float4*)&b_ih[HID + n0l];
        bh = *(const float4*)&b_hh[HID + n0l];
        seedZ[0] = (bi.x + bh.x) * LOG2E; seedZ[1] = (bi.y + bh.y) * LOG2E;
        seedZ[2] = (bi.z + bh.z) * LOG2E; seedZ[3] = (bi.w + bh.w) * LOG2E;
        bh = *(const float4*)&b_hh[2 * HID + n0l];
        seedN[0] = bh.x * 2.0f * LOG2E; seedN[1] = bh.y * 2.0f * LOG2E;
        seedN[2] = bh.z * 2.0f * LOG2E; seedN[3] = bh.w * 2.0f * LOG2E;
    }
    const float2 bin2 = *(const float2*)&b_ih[2 * HID + h0];
    const float bn0 = bin2.x * 2.0f * LOG2E, bn1 = bin2.y * 2.0f * LOG2E;

    // ---- swizzled LDS element offsets ----
    // Reads: row term uses br (=rr&7) so lanes rr and rr+8 alias the SAME
    // address (free broadcast) -> no exec-mask branch. Garbage-fed D cols
    // 8-15 are discarded by the rebalance exactly as before.
    const int re0 = br * 128 + (((0 * 4 + g) ^ br) << 3);
    const int re1 = br * 128 + (((1 * 4 + g) ^ br) << 3);
    const int re2 = br * 128 + (((2 * 4 + g) ^ br) << 3);
    const int re3 = br * 128 + (((3 * 4 + g) ^ br) << 3);
    const int we = br * 128 + ((((2 * j) + (g >> 1)) ^ br) << 3)
                 + 4 * (g & 1) + 2 * hi;

    // ---- init: hold regs + H buffer 0 ----
    const int batch = blockIdx.x * 8 + br;
    float2 h02 = *(const float2*)&latent[batch * HID + h0];
    float hold0 = h02.x, hold1 = h02.y;
    {
        unsigned v = (unsigned short)f2bf(hold0)
                   | ((unsigned)(unsigned short)f2bf(hold1) << 16);
        *(unsigned*)&Hl[0][we] = v;
    }
    __syncthreads();

    __hip_bfloat16* op = hs + ((size_t)batch * SEQ) * HID + h0;

    // One recurrence step: read SRC buffer, write DST buffer.
#define GRU_STEP(SRC, DST)                                                    \
    {                                                                         \
        bf16x8 hf0 = *(const bf16x8*)&SRC[re0];                               \
        bf16x8 hf1 = *(const bf16x8*)&SRC[re1];                               \
        bf16x8 hf2 = *(const bf16x8*)&SRC[re2];                               \
        bf16x8 hf3 = *(const bf16x8*)&SRC[re3];                               \
        f32x4 a0 = seedR, a1 = seedZ, a2 = seedN;                             \
        __builtin_amdgcn_s_setprio(1);                                        \
        a0 = __builtin_amdgcn_mfma_f32_16x16x32_bf16(wr0, hf0, a0, 0, 0, 0);  \
        a1 = __builtin_amdgcn_mfma_f32_16x16x32_bf16(wz0, hf0, a1, 0, 0, 0);  \
        a2 = __builtin_amdgcn_mfma_f32_16x16x32_bf16(wn0, hf0, a2, 0, 0, 0);  \
        a0 = __builtin_amdgcn_mfma_f32_16x16x32_bf16(wr1, hf1, a0, 0, 0, 0);  \
        a1 = __builtin_amdgcn_mfma_f32_16x16x32_bf16(wz1, hf1, a1, 0, 0, 0);  \
        a2 = __builtin_amdgcn_mfma_f32_16x16x32_bf16(wn1, hf1, a2, 0, 0, 0);  \
        a0 = __builtin_amdgcn_mfma_f32_16x16x32_bf16(wr2, hf2, a0, 0, 0, 0);  \
        a1 = __builtin_amdgcn_mfma_f32_16x16x32_bf16(wz2, hf2, a1, 0, 0, 0);  \
        a2 = __builtin_amdgcn_mfma_f32_16x16x32_bf16(wn2, hf2, a2, 0, 0, 0);  \
        a0 = __builtin_amdgcn_mfma_f32_16x16x32_bf16(wr3, hf3, a0, 0, 0, 0);  \
        a1 = __builtin_amdgcn_mfma_f32_16x16x32_bf16(wz3, hf3, a1, 0, 0, 0);  \
        a2 = __builtin_amdgcn_mfma_f32_16x16x32_bf16(wn3, hf3, a2, 0, 0, 0);  \
        __builtin_amdgcn_s_setprio(0);                                        \
        float gr0 = dpp_sel8(a0[0], a0[2]), gr1 = dpp_sel8(a0[1], a0[3]);     \
        float gz0 = dpp_sel8(a1[0], a1[2]), gz1 = dpp_sel8(a1[1], a1[3]);     \
        float gn0 = dpp_sel8(a2[0], a2[2]), gn1 = dpp_sel8(a2[1], a2[3]);     \
        float r0 = sigmoid_pre(gr0);                                          \
        float z0 = sigmoid_pre(gz0);                                          \
        float n0 = tanh_pre(fmaf(r0, gn0, bn0));                              \
        float hn0 = fmaf(z0, hold0 - n0, n0);                                 \
        hold0 = hn0;                                                          \
        float r1 = sigmoid_pre(gr1);                                          \
        float z1 = sigmoid_pre(gz1);                                          \
        float n1 = tanh_pre(fmaf(r1, gn1, bn1));                              \
        float hn1 = fmaf(z1, hold1 - n1, n1);                                 \
        hold1 = hn1;                                                          \
        unsigned v;                                                           \
        asm("v_cvt_pk_bf16_f32 %0, %1, %2" : "=v"(v) : "v"(hn0), "v"(hn1));   \
        *(unsigned*)&DST[we] = v;                                             \
        *(unsigned*)op = v;                                                   \
        op += HID;                                                            \
        asm volatile("s_waitcnt lgkmcnt(0)" ::: "memory");                    \
        __builtin_amdgcn_s_barrier();                                         \
        asm volatile("" ::: "memory");                                        \
    }

    const __hip_bfloat16* Hl0 = &Hl[0][0];
    const __hip_bfloat16* Hl1 = &Hl[1][0];
    __hip_bfloat16* Hl0w = &Hl[0][0];
    __hip_bfloat16* Hl1w = &Hl[1][0];

    #pragma unroll 1
    for (int t = 0; t < SEQ; t += 2) {
        GRU_STEP(Hl0, Hl1w);   // even step: buf0 -> buf1
        GRU_STEP(Hl1, Hl0w);   // odd  step: buf1 -> buf0
    }
#undef GRU_STEP
}

// ---------------------------------------------------------------------------
// Repack fc_W (f32 [512][128]) into bf16 MFMA fragment order:
//   wfrag[((ct*4 + q)*64 + lane)*8 + j] = bf16(fc_W[ct*16 + (lane&15)]
//                                                  [q*32 + (lane>>4)*8 + j])
// ---------------------------------------------------------------------------
__global__ void wprep(const float* __restrict__ fc_W,
                      __hip_bfloat16* __restrict__ wfrag)
{
    int t = blockIdx.x * 256 + threadIdx.x;      // 0..65535
    int j    = t & 7;
    int lane = (t >> 3) & 63;
    int q    = (t >> 9) & 3;
    int ct   = t >> 11;
    int n = ct * 16 + (lane & 15);
    int k = q * 32 + (lane >> 4) * 8 + j;
    unsigned short v = (unsigned short)f2bf(fc_W[n * HID + k]);
    wfrag[t] = __builtin_bit_cast(__hip_bfloat16, v);
}

// ---------------------------------------------------------------------------
// Projection: out[row][o] = sum_k hs[row][k] * fc_W[o][k] + fc_b[o]
// M = 131072, N = 512, K = 128. bf16 MFMA 16x16x32, operand-swapped.
// Nontemporal stores/loads. ~84us after the ~218us fixed harness overhead
// (round-8 discovery) -- near the write roofline.
// ---------------------------------------------------------------------------
__global__ __launch_bounds__(256) void proj_mfma(
    const __hip_bfloat16* __restrict__ hsb,    // [M][128] bf16
    const __hip_bfloat16* __restrict__ wfrag,  // fragment-ordered [32][4][64][8]
    const float* __restrict__ fc_b,            // [512]
    float* __restrict__ out)                   // [M][512] f32
{
    const int lane = threadIdx.x & 63;
    const int wave = threadIdx.x >> 6;
    const int m    = lane & 15;
    const int quad = lane >> 4;

    const long r0 = ((long)blockIdx.x * 4 + wave) * 32;

    bf16x8 bfrag[2][4];                         // hs rows as second operand
    #pragma unroll
    for (int rt = 0; rt < 2; rt++) {
        #pragma unroll
        for (int q = 0; q < 4; q++) {
            const bf16x8* p = (const bf16x8*)
                (hsb + (r0 + rt * 16 + m) * HID + q * 32 + quad * 8);
            bfrag[rt][q] = __builtin_nontemporal_load(p);   // single-use rows
        }
    }

    for (int ct2 = 0; ct2 < 16; ct2++) {
        const int ct0 = 2 * ct2;
        f32x4 acc00 = {0.f, 0.f, 0.f, 0.f};
        f32x4 acc01 = {0.f, 0.f, 0.f, 0.f};
        f32x4 acc10 = {0.f, 0.f, 0.f, 0.f};
        f32x4 acc11 = {0.f, 0.f, 0.f, 0.f};
        #pragma unroll
        for (int q = 0; q < 4; q++) {
            bf16x8 aw0 = *(const bf16x8*)(wfrag + (((ct0)     * 4 + q) * 64 + lane) * 8);
            bf16x8 aw1 = *(const bf16x8*)(wfrag + (((ct0 + 1) * 4 + q) * 64 + lane) * 8);
            acc00 = __builtin_amdgcn_mfma_f32_16x16x32_bf16(aw0, bfrag[0][q], acc00, 0, 0, 0);
            acc01 = __builtin_amdgcn_mfma_f32_16x16x32_bf16(aw1, bfrag[0][q], acc01, 0, 0, 0);
            acc10 = __builtin_amdgcn_mfma_f32_16x16x32_bf16(aw0, bfrag[1][q], acc10, 0, 0, 0);
            acc11 = __builtin_amdgcn_mfma_f32_16x16x32_bf16(aw1, bfrag[1][q], acc11, 0, 0, 0);
        }
        const int n0 = ct0 * 16 + quad * 4;
        const f32x4 bias0 = *(const f32x4*)&fc_b[n0];
        const f32x4 bias1 = *(const f32x4*)&fc_b[n0 + 16];
        float* row0 = &out[(r0 + m) * NOUT];
        float* row1 = &out[(r0 + 16 + m) * NOUT];
        f32x4 o;
        o = acc00 + bias0;
        __builtin_nontemporal_store(o, (f32x4*)&row0[n0]);
        o = acc01 + bias1;
        __builtin_nontemporal_store(o, (f32x4*)&row0[n0 + 16]);
        o = acc10 + bias0;
        __builtin_nontemporal_store(o, (f32x4*)&row1[n0]);
        o = acc11 + bias1;
        __builtin_nontemporal_store(o, (f32x4*)&row1[n0 + 16]);
    }
}

extern "C" void kernel_launch(void* const* d_in, const int* in_sizes, int n_in,
                              void* d_out, int out_size, void* d_ws, size_t ws_size,
                              hipStream_t stream) {
    const float* latent = (const float*)d_in[0];   // (64,128)
    const float* W_hh   = (const float*)d_in[1];   // (384,128)
    const float* b_ih   = (const float*)d_in[2];   // (384,)
    const float* b_hh   = (const float*)d_in[3];   // (384,)
    const float* fc_W   = (const float*)d_in[4];   // (512,128)
    const float* fc_b   = (const float*)d_in[5];   // (512,)
    float* out = (float*)d_out;                    // (64,2048,512)

    __hip_bfloat16* hsb   = (__hip_bfloat16*)d_ws;                   // 33.5 MB
    __hip_bfloat16* wfrag = (__hip_bfloat16*)((char*)d_ws + (size_t)BATCH * SEQ * HID * 2);

    wprep<<<256, 256, 0, stream>>>(fc_W, wfrag);
    gru_seq<<<8, 512, 0, stream>>>(latent, W_hh, b_ih, b_hh, hsb);

    const int M = BATCH * SEQ;                     // 131072
    proj_mfma<<<M / 128, 256, 0, stream>>>(hsb, wfrag, fc_b, out);
}

// Round 13
// 1015.759 us; speedup vs baseline: 2.1000x; 1.0096x over previous
//
#include <hip/hip_runtime.h>
#include <hip/hip_bf16.h>

#define HID 128
#define SEQ 2048
#define BATCH 64
#define NOUT 512

typedef __attribute__((ext_vector_type(8))) short bf16x8;
typedef __attribute__((ext_vector_type(4))) float f32x4;

__device__ __forceinline__ short f2bf(float f) {
    unsigned u = __float_as_uint(f);
    unsigned r = u + 0x7fffu + ((u >> 16) & 1u);   // RNE
    return (short)(r >> 16);
}

// Hardware reciprocal: verified round 9 (gru 1380->937us). ~2^-22 error.
__device__ __forceinline__ float fast_rcp(float x) {
    float y;
    asm("v_rcp_f32 %0, %1" : "=v"(y) : "v"(x));
    return y;
}

// v_exp_f32 IS exp2 on AMD; log2e/2log2e pre-folded into W frags + seeds
// (verified round 11: 875->818us). Zero multiplies in the activation chain.
__device__ __forceinline__ float exp2_neg(float x) {   // 2^(-x)
    float y;
    asm("v_exp_f32 %0, -%1" : "=v"(y) : "v"(x));
    return y;
}
__device__ __forceinline__ float exp2_pos(float x) {   // 2^x
    float y;
    asm("v_exp_f32 %0, %1" : "=v"(y) : "v"(x));
    return y;
}
__device__ __forceinline__ float sigmoid_pre(float xp) {   // xp = log2e*a
    return fast_rcp(1.0f + exp2_neg(xp));
}
__device__ __forceinline__ float tanh_pre(float yp) {      // yp = 2log2e*a
    return fmaf(-2.0f, fast_rcp(exp2_pos(yp) + 1.0f), 1.0f);
}

#define LOG2E 1.4426950408889634f

// Rebalance select in ONE bank-masked DPP (verified round 10):
// lanes 8-15 of each 16-group (banks 2,3) take lane^8's `hiv` via
// ROW_ROR:8; lanes 0-7 keep `lo`.
__device__ __forceinline__ float dpp_sel8(float lo, float hiv) {
    int y = __builtin_amdgcn_update_dpp(__builtin_bit_cast(int, lo),
                                        __builtin_bit_cast(int, hiv),
                                        0x128, 0xF, 0xC, false);
    return __builtin_bit_cast(float, y);
}

// One MFMA A-fragment from an f32 [rows][128] matrix, scaled then
// RNE-rounded to bf16.
__device__ __forceinline__ bf16x8 load_wfrag(const float* __restrict__ W,
                                             int row, int kcol, float scale) {
    const float* wp = W + (size_t)row * HID + kcol;
    float4 x = *(const float4*)wp;
    float4 y = *(const float4*)(wp + 4);
    bf16x8 f;
    f[0] = f2bf(x.x * scale); f[1] = f2bf(x.y * scale);
    f[2] = f2bf(x.z * scale); f[3] = f2bf(x.w * scale);
    f[4] = f2bf(y.x * scale); f[5] = f2bf(y.y * scale);
    f[6] = f2bf(y.z * scale); f[7] = f2bf(y.w * scale);
    return f;
}

// ---------------------------------------------------------------------------
// MFMA GRU recurrence. 8 blocks x 8 batches; 512 threads = 8 waves.
// Cost model (round-12 verified, step = 847 cyc):
//   matrix 466 (96 MFMA/CU-step, floor for this decomposition) +
//   post-barrier ds_read ~120 + act chain ~130 + write/barrier ~70
//   + aliased-read bank conflicts ~30 (round-12 counter: 2^21 total =
//   32 cyc per aliased ds_read_b128 -- same-address broadcast is NOT
//   free at b128/16B granularity, unlike b32).
// Round-13: restore exec-masked H reads (rr<8; stale regs in upper lanes
// feed only the D columns 8-15 that dpp_sel8 discards -- the verified
// round-6..11 pattern) on the round-12 unrolled skeleton.
// Structural alternatives rejected by arithmetic: N-split across CUs
// (saves 233 matrix cyc, costs >=200 cyc cross-CU handshake + coherence
// risk); 2 blocks/CU overlap (matrix pipe 932 > 847 wall); batch packing
// (MFMA count fixed at 96 by NxK tiling regardless of batch occupancy).
// ---------------------------------------------------------------------------
__global__ __launch_bounds__(512, 1) void gru_seq(
    const float* __restrict__ latent,   // [BATCH][HID]
    const float* __restrict__ W_hh,     // [3*HID][HID]
    const float* __restrict__ b_ih,     // [3*HID]
    const float* __restrict__ b_hh,     // [3*HID]
    __hip_bfloat16* __restrict__ hs)    // [BATCH][SEQ][HID]  (bf16)
{
    const int tid  = threadIdx.x;          // 0..511
    const int j    = tid >> 6;             // wave 0..7 -> n-tiles {j,j+8,j+16}
    const int lane = tid & 63;
    const int rr   = lane & 15;            // operand 16-axis / D batch col
    const int g    = lane >> 4;            // 0..3
    const int hi   = (lane >> 3) & 1;      // upper half of 16-group
    const int br   = rr & 7;               // batch row 0..7
    const int h0   = 16 * j + 4 * g + 2 * hi;  // this lane's 2 h columns
    const int n0l  = 16 * j + 4 * g;           // this lane's 4 gate rows

    // [2 buffers][16 rows][128 cols] bf16, 16B-block swizzled within rows
    __shared__ __align__(16) __hip_bfloat16 Hl[2][2048];

    // ---- W fragments: 12 named registers; r/z scaled log2e, n by 2log2e ----
    const int wrow = j * 16 + rr;
    bf16x8 wr0 = load_wfrag(W_hh, wrow,       0 * 32 + g * 8, LOG2E);
    bf16x8 wr1 = load_wfrag(W_hh, wrow,       1 * 32 + g * 8, LOG2E);
    bf16x8 wr2 = load_wfrag(W_hh, wrow,       2 * 32 + g * 8, LOG2E);
    bf16x8 wr3 = load_wfrag(W_hh, wrow,       3 * 32 + g * 8, LOG2E);
    bf16x8 wz0 = load_wfrag(W_hh, wrow + 128, 0 * 32 + g * 8, LOG2E);
    bf16x8 wz1 = load_wfrag(W_hh, wrow + 128, 1 * 32 + g * 8, LOG2E);
    bf16x8 wz2 = load_wfrag(W_hh, wrow + 128, 2 * 32 + g * 8, LOG2E);
    bf16x8 wz3 = load_wfrag(W_hh, wrow + 128, 3 * 32 + g * 8, LOG2E);
    bf16x8 wn0 = load_wfrag(W_hh, wrow + 256, 0 * 32 + g * 8, 2.0f * LOG2E);
    bf16x8 wn1 = load_wfrag(W_hh, wrow + 256, 1 * 32 + g * 8, 2.0f * LOG2E);
    bf16x8 wn2 = load_wfrag(W_hh, wrow + 256, 2 * 32 + g * 8, 2.0f * LOG2E);
    bf16x8 wn3 = load_wfrag(W_hh, wrow + 256, 3 * 32 + g * 8, 2.0f * LOG2E);

    // ---- accumulator bias seeds, matching scales ----
    f32x4 seedR, seedZ, seedN;
    {
        float4 bi = *(const float4*)&b_ih[n0l];
        float4 bh = *(const float4*)&b_hh[n0l];
        seedR[0] = (bi.x + bh.x) * LOG2E; seedR[1] = (bi.y + bh.y) * LOG2E;
        seedR[2] = (bi.z + bh.z) * LOG2E; seedR[3] = (bi.w + bh.w) * LOG2E;
        bi = *(const float4*)&b_ih[HID + n0l];
        bh = *(const float4*)&b_hh[HID + n0l];
        seedZ[0] = (bi.x + bh.x) * LOG2E; seedZ[1] = (bi.y + bh.y) * LOG2E;
        seedZ[2] = (bi.z + bh.z) * LOG2E; seedZ[3] = (bi.w + bh.w) * LOG2E;
        bh = *(const float4*)&b_hh[2 * HID + n0l];
        seedN[0] = bh.x * 2.0f * LOG2E; seedN[1] = bh.y * 2.0f * LOG2E;
        seedN[2] = bh.z * 2.0f * LOG2E; seedN[3] = bh.w * 2.0f * LOG2E;
    }
    const float2 bin2 = *(const float2*)&b_ih[2 * HID + h0];
    const float bn0 = bin2.x * 2.0f * LOG2E, bn1 = bin2.y * 2.0f * LOG2E;

    // ---- swizzled LDS element offsets (rows 0-7 only; reads masked) ----
    const int re0 = br * 128 + (((0 * 4 + g) ^ br) << 3);
    const int re1 = br * 128 + (((1 * 4 + g) ^ br) << 3);
    const int re2 = br * 128 + (((2 * 4 + g) ^ br) << 3);
    const int re3 = br * 128 + (((3 * 4 + g) ^ br) << 3);
    const int we = br * 128 + ((((2 * j) + (g >> 1)) ^ br) << 3)
                 + 4 * (g & 1) + 2 * hi;

    // ---- init: hold regs + H buffer 0 ----
    const int batch = blockIdx.x * 8 + br;
    float2 h02 = *(const float2*)&latent[batch * HID + h0];
    float hold0 = h02.x, hold1 = h02.y;
    {
        unsigned v = (unsigned short)f2bf(hold0)
                   | ((unsigned)(unsigned short)f2bf(hold1) << 16);
        *(unsigned*)&Hl[0][we] = v;
    }
    __syncthreads();

    __hip_bfloat16* op = hs + ((size_t)batch * SEQ) * HID + h0;

    // Persistent H fragments: masked reads leave stale values in rr>=8
    // lanes; those feed only D columns 8-15, discarded by dpp_sel8.
    bf16x8 hf0 = {}, hf1 = {}, hf2 = {}, hf3 = {};

#define GRU_STEP(SRC, DST)                                                    \
    {                                                                         \
        if (rr < 8) {                                                         \
            hf0 = *(const bf16x8*)&SRC[re0];                                  \
            hf1 = *(const bf16x8*)&SRC[re1];                                  \
            hf2 = *(const bf16x8*)&SRC[re2];                                  \
            hf3 = *(const bf16x8*)&SRC[re3];                                  \
        }                                                                     \
        f32x4 a0 = seedR, a1 = seedZ, a2 = seedN;                             \
        __builtin_amdgcn_s_setprio(1);                                        \
        a0 = __builtin_amdgcn_mfma_f32_16x16x32_bf16(wr0, hf0, a0, 0, 0, 0);  \
        a1 = __builtin_amdgcn_mfma_f32_16x16x32_bf16(wz0, hf0, a1, 0, 0, 0);  \
        a2 = __builtin_amdgcn_mfma_f32_16x16x32_bf16(wn0, hf0, a2, 0, 0, 0);  \
        a0 = __builtin_amdgcn_mfma_f32_16x16x32_bf16(wr1, hf1, a0, 0, 0, 0);  \
        a1 = __builtin_amdgcn_mfma_f32_16x16x32_bf16(wz1, hf1, a1, 0, 0, 0);  \
        a2 = __builtin_amdgcn_mfma_f32_16x16x32_bf16(wn1, hf1, a2, 0, 0, 0);  \
        a0 = __builtin_amdgcn_mfma_f32_16x16x32_bf16(wr2, hf2, a0, 0, 0, 0);  \
        a1 = __builtin_amdgcn_mfma_f32_16x16x32_bf16(wz2, hf2, a1, 0, 0, 0);  \
        a2 = __builtin_amdgcn_mfma_f32_16x16x32_bf16(wn2, hf2, a2, 0, 0, 0);  \
        a0 = __builtin_amdgcn_mfma_f32_16x16x32_bf16(wr3, hf3, a0, 0, 0, 0);  \
        a1 = __builtin_amdgcn_mfma_f32_16x16x32_bf16(wz3, hf3, a1, 0, 0, 0);  \
        a2 = __builtin_amdgcn_mfma_f32_16x16x32_bf16(wn3, hf3, a2, 0, 0, 0);  \
        __builtin_amdgcn_s_setprio(0);                                        \
        float gr0 = dpp_sel8(a0[0], a0[2]), gr1 = dpp_sel8(a0[1], a0[3]);     \
        float gz0 = dpp_sel8(a1[0], a1[2]), gz1 = dpp_sel8(a1[1], a1[3]);     \
        float gn0 = dpp_sel8(a2[0], a2[2]), gn1 = dpp_sel8(a2[1], a2[3]);     \
        float r0 = sigmoid_pre(gr0);                                          \
        float z0 = sigmoid_pre(gz0);                                          \
        float n0 = tanh_pre(fmaf(r0, gn0, bn0));                              \
        float hn0 = fmaf(z0, hold0 - n0, n0);                                 \
        hold0 = hn0;                                                          \
        float r1 = sigmoid_pre(gr1);                                          \
        float z1 = sigmoid_pre(gz1);                                          \
        float n1 = tanh_pre(fmaf(r1, gn1, bn1));                              \
        float hn1 = fmaf(z1, hold1 - n1, n1);                                 \
        hold1 = hn1;                                                          \
        unsigned v;                                                           \
        asm("v_cvt_pk_bf16_f32 %0, %1, %2" : "=v"(v) : "v"(hn0), "v"(hn1));   \
        *(unsigned*)&DST[we] = v;                                             \
        *(unsigned*)op = v;                                                   \
        op += HID;                                                            \
        asm volatile("s_waitcnt lgkmcnt(0)" ::: "memory");                    \
        __builtin_amdgcn_s_barrier();                                         \
        asm volatile("" ::: "memory");                                        \
    }

    const __hip_bfloat16* Hl0 = &Hl[0][0];
    const __hip_bfloat16* Hl1 = &Hl[1][0];
    __hip_bfloat16* Hl0w = &Hl[0][0];
    __hip_bfloat16* Hl1w = &Hl[1][0];

    #pragma unroll 1
    for (int t = 0; t < SEQ; t += 2) {
        GRU_STEP(Hl0, Hl1w);   // even step: buf0 -> buf1
        GRU_STEP(Hl1, Hl0w);   // odd  step: buf1 -> buf0
    }
#undef GRU_STEP
}

// ---------------------------------------------------------------------------
// Repack fc_W (f32 [512][128]) into bf16 MFMA fragment order:
//   wfrag[((ct*4 + q)*64 + lane)*8 + j] = bf16(fc_W[ct*16 + (lane&15)]
//                                                  [q*32 + (lane>>4)*8 + j])
// ---------------------------------------------------------------------------
__global__ void wprep(const float* __restrict__ fc_W,
                      __hip_bfloat16* __restrict__ wfrag)
{
    int t = blockIdx.x * 256 + threadIdx.x;      // 0..65535
    int j    = t & 7;
    int lane = (t >> 3) & 63;
    int q    = (t >> 9) & 3;
    int ct   = t >> 11;
    int n = ct * 16 + (lane & 15);
    int k = q * 32 + (lane >> 4) * 8 + j;
    unsigned short v = (unsigned short)f2bf(fc_W[n * HID + k]);
    wfrag[t] = __builtin_bit_cast(__hip_bfloat16, v);
}

// ---------------------------------------------------------------------------
// Projection: out[row][o] = sum_k hs[row][k] * fc_W[o][k] + fc_b[o]
// M = 131072, N = 512, K = 128. bf16 MFMA 16x16x32, operand-swapped.
// Nontemporal stores/loads. ~84us after the ~218us fixed harness overhead
// (round-8 discovery) -- near the write roofline.
// ---------------------------------------------------------------------------
__global__ __launch_bounds__(256) void proj_mfma(
    const __hip_bfloat16* __restrict__ hsb,    // [M][128] bf16
    const __hip_bfloat16* __restrict__ wfrag,  // fragment-ordered [32][4][64][8]
    const float* __restrict__ fc_b,            // [512]
    float* __restrict__ out)                   // [M][512] f32
{
    const int lane = threadIdx.x & 63;
    const int wave = threadIdx.x >> 6;
    const int m    = lane & 15;
    const int quad = lane >> 4;

    const long r0 = ((long)blockIdx.x * 4 + wave) * 32;

    bf16x8 bfrag[2][4];                         // hs rows as second operand
    #pragma unroll
    for (int rt = 0; rt < 2; rt++) {
        #pragma unroll
        for (int q = 0; q < 4; q++) {
            const bf16x8* p = (const bf16x8*)
                (hsb + (r0 + rt * 16 + m) * HID + q * 32 + quad * 8);
            bfrag[rt][q] = __builtin_nontemporal_load(p);   // single-use rows
        }
    }

    for (int ct2 = 0; ct2 < 16; ct2++) {
        const int ct0 = 2 * ct2;
        f32x4 acc00 = {0.f, 0.f, 0.f, 0.f};
        f32x4 acc01 = {0.f, 0.f, 0.f, 0.f};
        f32x4 acc10 = {0.f, 0.f, 0.f, 0.f};
        f32x4 acc11 = {0.f, 0.f, 0.f, 0.f};
        #pragma unroll
        for (int q = 0; q < 4; q++) {
            bf16x8 aw0 = *(const bf16x8*)(wfrag + (((ct0)     * 4 + q) * 64 + lane) * 8);
            bf16x8 aw1 = *(const bf16x8*)(wfrag + (((ct0 + 1) * 4 + q) * 64 + lane) * 8);
            acc00 = __builtin_amdgcn_mfma_f32_16x16x32_bf16(aw0, bfrag[0][q], acc00, 0, 0, 0);
            acc01 = __builtin_amdgcn_mfma_f32_16x16x32_bf16(aw1, bfrag[0][q], acc01, 0, 0, 0);
            acc10 = __builtin_amdgcn_mfma_f32_16x16x32_bf16(aw0, bfrag[1][q], acc10, 0, 0, 0);
            acc11 = __builtin_amdgcn_mfma_f32_16x16x32_bf16(aw1, bfrag[1][q], acc11, 0, 0, 0);
        }
        const int n0 = ct0 * 16 + quad * 4;
        const f32x4 bias0 = *(const f32x4*)&fc_b[n0];
        const f32x4 bias1 = *(const f32x4*)&fc_b[n0 + 16];
        float* row0 = &out[(r0 + m) * NOUT];
        float* row1 = &out[(r0 + 16 + m) * NOUT];
        f32x4 o;
        o = acc00 + bias0;
        __builtin_nontemporal_store(o, (f32x4*)&row0[n0]);
        o = acc01 + bias1;
        __builtin_nontemporal_store(o, (f32x4*)&row0[n0 + 16]);
        o = acc10 + bias0;
        __builtin_nontemporal_store(o, (f32x4*)&row1[n0]);
        o = acc11 + bias1;
        __builtin_nontemporal_store(o, (f32x4*)&row1[n0 + 16]);
    }
}

extern "C" void kernel_launch(void* const* d_in, const int* in_sizes, int n_in,
                              void* d_out, int out_size, void* d_ws, size_t ws_size,
                              hipStream_t stream) {
    const float* latent = (const float*)d_in[0];   // (64,128)
    const float* W_hh   = (const float*)d_in[1];   // (384,128)
    const float* b_ih   = (const float*)d_in[2];   // (384,)
    const float* b_hh   = (const float*)d_in[3];   // (384,)
    const float* fc_W   = (const float*)d_in[4];   // (512,128)
    const float* fc_b   = (const float*)d_in[5];   // (512,)
    float* out = (float*)d_out;                    // (64,2048,512)

    __hip_bfloat16* hsb   = (__hip_bfloat16*)d_ws;                   // 33.5 MB
    __hip_bfloat16* wfrag = (__hip_bfloat16*)((char*)d_ws + (size_t)BATCH * SEQ * HID * 2);

    wprep<<<256, 256, 0, stream>>>(fc_W, wfrag);
    gru_seq<<<8, 512, 0, stream>>>(latent, W_hh, b_ih, b_hh, hsb);

    const int M = BATCH * SEQ;                     // 131072
    proj_mfma<<<M / 128, 256, 0, stream>>>(hsb, wfrag, fc_b, out);
}